// Round 21
// baseline (1139.790 us; speedup 1.0000x reference)
//
#include <hip/hip_runtime.h>
#include <hip/hip_fp16.h>
#include <stdint.h>

typedef unsigned int u32;
typedef unsigned long long u64;
typedef unsigned char u8;

#define NCLS 5
#define KMX 5
#define DD 32
#define LBN 4
#define KIT 5
#define MAXA 2048
#define CKK 25
#define NBLKA 256
#define SCPAD 36
#define ACAP 4096
#define UKTHR ((1u << 23) + 1u - (1u << 15))

struct RKeys {
  u32 ki[LBN][2];
  u32 kf[LBN][2];
  u32 k1000[2];
  u32 k2000[2];
  u32 k2001[2];
};

struct SelState {
  u32 prefix1, rank1, prefix21, rank2, pivot_sv, target, M, ncand, ncand2;
};

// ---------------- threefry2x32 (bit-exact JAX) ----------------
__host__ __device__ inline void tf2x32(u32 k0, u32 k1, u32 x0, u32 x1, u32* o0, u32* o1) {
  u32 ks2 = k0 ^ k1 ^ 0x1BD11BDAu;
  u32 ks[3] = {k0, k1, ks2};
  x0 += k0; x1 += k1;
  const int rotA[4] = {13, 15, 26, 6};
  const int rotB[4] = {17, 29, 16, 24};
#pragma unroll
  for (int g = 0; g < 5; ++g) {
#pragma unroll
    for (int j = 0; j < 4; ++j) {
      int r = (g & 1) ? rotB[j] : rotA[j];
      x0 += x1;
      x1 = (x1 << r) | (x1 >> (32 - r));
      x1 ^= x0;
    }
    x0 += ks[(g + 1) % 3];
    x1 += ks[(g + 2) % 3] + (u32)(g + 1);
  }
  *o0 = x0; *o1 = x1;
}

// Monotone surrogate key for JAX gumbel (order-preserving; 0 = invalid).
__device__ inline u32 jax_ukey(u32 k0, u32 k1, u32 half, u32 idx) {
  bool hi = (idx >= half);
  u32 c0 = hi ? (idx - half) : idx;
  u32 c1 = hi ? idx : (idx + half);
  u32 o0, o1;
  tf2x32(k0, k1, c0, c1, &o0, &o1);
  u32 bits = hi ? o1 : o0;
  return (bits >> 9) + 1u;
}

#define INS5(kk, a0, a1, a2, a3, a4) do { u64 _k = (kk); \
  if (_k > a4) { a4 = _k; u64 _t; \
    if (a4 > a3) { _t = a3; a3 = a4; a4 = _t; } \
    if (a3 > a2) { _t = a2; a2 = a3; a3 = _t; } \
    if (a2 > a1) { _t = a1; a1 = a2; a2 = _t; } \
    if (a1 > a0) { _t = a0; a0 = a1; a1 = _t; } } } while (0)

#define WMERGE5(off, a0, a1, a2, a3, a4) do { \
  u64 r0 = __shfl_xor(a0, off, 64), r1 = __shfl_xor(a1, off, 64), \
      r2 = __shfl_xor(a2, off, 64), r3 = __shfl_xor(a3, off, 64), \
      r4 = __shfl_xor(a4, off, 64); \
  INS5(r0, a0, a1, a2, a3, a4); INS5(r1, a0, a1, a2, a3, a4); \
  INS5(r2, a0, a1, a2, a3, a4); INS5(r3, a0, a1, a2, a3, a4); \
  INS5(r4, a0, a1, a2, a3, a4); } while (0)

#define WMERGE_ALL(a0,a1,a2,a3,a4) do { \
  WMERGE5(32,a0,a1,a2,a3,a4); WMERGE5(16,a0,a1,a2,a3,a4); WMERGE5(8,a0,a1,a2,a3,a4); \
  WMERGE5(4,a0,a1,a2,a3,a4); WMERGE5(2,a0,a1,a2,a3,a4); WMERGE5(1,a0,a1,a2,a3,a4); } while (0)

__device__ inline float rsum32(float v) {
#pragma unroll
  for (int o = 16; o; o >>= 1) v += __shfl_xor(v, o, 32);
  return v;
}

__device__ inline float rsum64(float v) {
#pragma unroll
  for (int o = 32; o; o >>= 1) v += __shfl_xor(v, o, 64);
  return v;
}

// fp16 pack/unpack: 4 halves in a uint2
__device__ inline float4 h8tof4(uint2 u) {
  __half2 a = *reinterpret_cast<__half2*>(&u.x);
  __half2 b = *reinterpret_cast<__half2*>(&u.y);
  float2 fa = __half22float2(a), fb = __half22float2(b);
  return make_float4(fa.x, fa.y, fb.x, fb.y);
}
__device__ inline uint2 f4toh8(float4 f) {
  __half2 a = __float22half2_rn(make_float2(f.x, f.y));
  __half2 b = __float22half2_rn(make_float2(f.z, f.w));
  uint2 u;
  u.x = *reinterpret_cast<u32*>(&a);
  u.y = *reinterpret_cast<u32*>(&b);
  return u;
}

// ---------------- kernels ----------------

__global__ void k_protos(const float* __restrict__ protos, float* __restrict__ protn, float* __restrict__ compact) {
  __shared__ float pl[CKK * DD];
  __shared__ float rn[CKK];
  __shared__ float red[4];
  int tid = threadIdx.x;  // 256
  for (int t = tid; t < CKK * DD; t += 256) pl[t] = protos[t];
  __syncthreads();
  if (tid < CKK) {
    float s = 0.f;
    for (int d = 0; d < DD; ++d) { float x = pl[tid * DD + d]; s += x * x; }
    rn[tid] = sqrtf(s + 1e-12f);
  }
  __syncthreads();
  for (int t = tid; t < CKK * DD; t += 256) {
    float v = pl[t] / rn[t / DD];
    pl[t] = v;
    protn[t] = v;
  }
  __syncthreads();
  float part = 0.f;
  if (tid < (NCLS - 1) * DD) {
    int c = 1 + tid / DD;
    int d = tid % DD;
    float m = 0.f;
#pragma unroll
    for (int k = 0; k < KMX; ++k) m += pl[(c * KMX + k) * DD + d];
    m *= (1.0f / KMX);
    float v = 0.f;
#pragma unroll
    for (int k = 0; k < KMX; ++k) { float df = pl[(c * KMX + k) * DD + d] - m; v += df * df; }
    part = v * (1.0f / (KMX - 1)) * (1.0f / DD);
  }
#pragma unroll
  for (int o = 32; o; o >>= 1) part += __shfl_xor(part, o, 64);
  int wid = tid >> 6;
  if ((tid & 63) == 0) red[wid] = part;
  __syncthreads();
  if (tid == 0) compact[0] = red[0] + red[1] + red[2] + red[3];
}

// ---- top-5 (kind 0 / init only): threshold-gated register scan + exact rescue ----
// Main pass also materializes ci8[n] (class index 0..3, 255 = unlabeled).

#define T5PROC_THR(gv_, nn_, cv_) do { \
  int ci = (gv_ == lb0) ? 0 : (gv_ == lb1) ? 1 : (gv_ == lb2) ? 2 : (gv_ == lb3) ? 3 : -1; \
  cv_ = (u8)(ci < 0 ? 255 : ci); \
  if (ci >= 0) { \
    u32 k0 = (ci & 2) ? ((ci & 1) ? ka3 : ka2) : ((ci & 1) ? ka1 : ka0); \
    u32 k1 = (ci & 2) ? ((ci & 1) ? kb3 : kb2) : ((ci & 1) ? kb1 : kb0); \
    u32 uk = jax_ukey(k0, k1, half, (u32)(nn_)); \
    if (uk >= UKTHR) { \
      u64 key = ((u64)uk << 32) | (u32)(~(u32)(nn_)); \
      if (ci == 0) { INS5(key, A0, A1, A2, A3, A4); } \
      else if (ci == 1) { INS5(key, B0, B1, B2, B3, B4); } \
      else if (ci == 2) { INS5(key, C0, C1, C2, C3, C4); } \
      else { INS5(key, D0, D1, D2, D3, D4); } \
    } \
  } } while (0)

#define T5PROC(gv_, nn_) do { \
  int ci = (gv_ == lb0) ? 0 : (gv_ == lb1) ? 1 : (gv_ == lb2) ? 2 : (gv_ == lb3) ? 3 : -1; \
  if (ci >= 0) { \
    u32 k0 = (ci & 2) ? ((ci & 1) ? ka3 : ka2) : ((ci & 1) ? ka1 : ka0); \
    u32 k1 = (ci & 2) ? ((ci & 1) ? kb3 : kb2) : ((ci & 1) ? kb1 : kb0); \
    u32 uk = jax_ukey(k0, k1, half, (u32)(nn_)); \
    u64 key = ((u64)uk << 32) | (u32)(~(u32)(nn_)); \
    if (ci == 0) { INS5(key, A0, A1, A2, A3, A4); } \
    else if (ci == 1) { INS5(key, B0, B1, B2, B3, B4); } \
    else if (ci == 2) { INS5(key, C0, C1, C2, C3, C4); } \
    else { INS5(key, D0, D1, D2, D3, D4); } \
  } } while (0)

#define T5_TAIL_STORE() \
  WMERGE_ALL(A0,A1,A2,A3,A4); \
  WMERGE_ALL(B0,B1,B2,B3,B4); \
  WMERGE_ALL(C0,C1,C2,C3,C4); \
  WMERGE_ALL(D0,D1,D2,D3,D4); \
  __shared__ u64 wbuf[4][20]; \
  int tid = threadIdx.x; \
  int wid = tid >> 6; \
  if ((tid & 63) == 0) { \
    u64* w = wbuf[wid]; \
    w[0]=A0; w[1]=A1; w[2]=A2; w[3]=A3; w[4]=A4; \
    w[5]=B0; w[6]=B1; w[7]=B2; w[8]=B3; w[9]=B4; \
    w[10]=C0; w[11]=C1; w[12]=C2; w[13]=C3; w[14]=C4; \
    w[15]=D0; w[16]=D1; w[17]=D2; w[18]=D3; w[19]=D4; \
  } \
  __syncthreads(); \
  if (tid == 0) { \
    _Pragma("unroll") \
    for (int w = 1; w < 4; ++w) { \
      _Pragma("unroll") \
      for (int j = 0; j < 5; ++j) { \
        u64 ka = wbuf[w][j];      INS5(ka, A0, A1, A2, A3, A4); \
        u64 kb = wbuf[w][5 + j];  INS5(kb, B0, B1, B2, B3, B4); \
        u64 kc = wbuf[w][10 + j]; INS5(kc, C0, C1, C2, C3, C4); \
        u64 kd = wbuf[w][15 + j]; INS5(kd, D0, D1, D2, D3, D4); \
      } \
    } \
    size_t nb = gridDim.x; \
    u64* o0 = outA + ((size_t)0 * nb + blockIdx.x) * 5; \
    o0[0]=A0; o0[1]=A1; o0[2]=A2; o0[3]=A3; o0[4]=A4; \
    u64* o1 = outA + ((size_t)1 * nb + blockIdx.x) * 5; \
    o1[0]=B0; o1[1]=B1; o1[2]=B2; o1[3]=B3; o1[4]=B4; \
    u64* o2 = outA + ((size_t)2 * nb + blockIdx.x) * 5; \
    o2[0]=C0; o2[1]=C1; o2[2]=C2; o2[3]=C3; o2[4]=C4; \
    u64* o3 = outA + ((size_t)3 * nb + blockIdx.x) * 5; \
    o3[0]=D0; o3[1]=D1; o3[2]=D2; o3[3]=D3; o3[4]=D4; \
  }

#define T5_HEAD() \
  int lb0 = labeled[0], lb1 = labeled[1], lb2 = labeled[2], lb3 = labeled[3]; \
  u32 half = (u32)(N / 2); \
  u32 ka0 = RK.ki[0][0], kb0 = RK.ki[0][1]; \
  u32 ka1 = RK.ki[1][0], kb1 = RK.ki[1][1]; \
  u32 ka2 = RK.ki[2][0], kb2 = RK.ki[2][1]; \
  u32 ka3 = RK.ki[3][0], kb3 = RK.ki[3][1]; \
  u64 A0=0,A1=0,A2=0,A3=0,A4=0; \
  u64 B0=0,B1=0,B2=0,B3=0,B4=0; \
  u64 C0=0,C1=0,C2=0,C3=0,C4=0; \
  u64 D0=0,D1=0,D2=0,D3=0,D4=0;

__global__ void k_top5A(const int* __restrict__ gt, const int* __restrict__ labeled,
                        RKeys RK, u64* __restrict__ outA, u8* __restrict__ ci8, int N) {
  T5_HEAD()
  int Nq = N >> 2;
  int stride = gridDim.x * blockDim.x;
  for (int q = blockIdx.x * blockDim.x + threadIdx.x; q < Nq; q += stride) {
    int4 g4 = ((const int4*)gt)[q];
    int n = q << 2;
    u8 c0v, c1v, c2v, c3v;
    T5PROC_THR(g4.x, n, c0v);
    T5PROC_THR(g4.y, n + 1, c1v);
    T5PROC_THR(g4.z, n + 2, c2v);
    T5PROC_THR(g4.w, n + 3, c3v);
    ((uchar4*)ci8)[q] = make_uchar4(c0v, c1v, c2v, c3v);
  }
  T5_TAIL_STORE()
}

__global__ void k_top5B(const u64* __restrict__ outA, u32* __restrict__ rescue,
                        u64* __restrict__ top5F, int nblk) {
  int i = blockIdx.x;  // class
  const u64* src = outA + (size_t)i * nblk * 5;
  u64 t0 = 0, t1 = 0, t2 = 0, t3 = 0, t4 = 0;
  int tot = nblk * 5;
  for (int j = threadIdx.x; j < tot; j += blockDim.x) { u64 k = src[j]; INS5(k, t0, t1, t2, t3, t4); }
  WMERGE_ALL(t0, t1, t2, t3, t4);
  __shared__ u64 wbuf[4 * 5];
  int tid = threadIdx.x;
  int wid = tid >> 6;
  if ((tid & 63) == 0) {
    wbuf[wid * 5 + 0] = t0; wbuf[wid * 5 + 1] = t1; wbuf[wid * 5 + 2] = t2;
    wbuf[wid * 5 + 3] = t3; wbuf[wid * 5 + 4] = t4;
  }
  __syncthreads();
  if (tid == 0) {
#pragma unroll
    for (int w = 1; w < 4; ++w)
#pragma unroll
      for (int j = 0; j < 5; ++j) { u64 k = wbuf[w * 5 + j]; INS5(k, t0, t1, t2, t3, t4); }
    u64* o = top5F + (size_t)i * 5;
    o[0] = t0; o[1] = t1; o[2] = t2; o[3] = t3; o[4] = t4;
    if (t4 == 0ULL) atomicOr(rescue, 1u << i);
  }
}

__global__ void k_top5A_resc(const int* __restrict__ gt, const int* __restrict__ labeled,
                             RKeys RK, const u32* __restrict__ rescue,
                             u64* __restrict__ outA, int N) {
  if ((rescue[0] & 0xFu) == 0u) return;
  T5_HEAD()
  int Nq = N >> 2;
  int stride = gridDim.x * blockDim.x;
  for (int q = blockIdx.x * blockDim.x + threadIdx.x; q < Nq; q += stride) {
    int4 g4 = ((const int4*)gt)[q];
    int n = q << 2;
    T5PROC(g4.x, n);
    T5PROC(g4.y, n + 1);
    T5PROC(g4.z, n + 2);
    T5PROC(g4.w, n + 3);
  }
  T5_TAIL_STORE()
}

__global__ void k_top5B_resc(const u64* __restrict__ outA, const u32* __restrict__ rescue,
                             u64* __restrict__ top5F, int nblk) {
  int i = blockIdx.x;
  if (!((rescue[0] >> i) & 1u)) return;
  const u64* src = outA + (size_t)i * nblk * 5;
  u64 t0 = 0, t1 = 0, t2 = 0, t3 = 0, t4 = 0;
  int tot = nblk * 5;
  for (int j = threadIdx.x; j < tot; j += blockDim.x) { u64 k = src[j]; INS5(k, t0, t1, t2, t3, t4); }
  WMERGE_ALL(t0, t1, t2, t3, t4);
  __shared__ u64 wbuf[4 * 5];
  int tid = threadIdx.x;
  int wid = tid >> 6;
  if ((tid & 63) == 0) {
    wbuf[wid * 5 + 0] = t0; wbuf[wid * 5 + 1] = t1; wbuf[wid * 5 + 2] = t2;
    wbuf[wid * 5 + 3] = t3; wbuf[wid * 5 + 4] = t4;
  }
  __syncthreads();
  if (tid == 0) {
#pragma unroll
    for (int w = 1; w < 4; ++w)
#pragma unroll
      for (int j = 0; j < 5; ++j) { u64 k = wbuf[w * 5 + j]; INS5(k, t0, t1, t2, t3, t4); }
    u64* o = top5F + (size_t)i * 5;
    o[0] = t0; o[1] = t1; o[2] = t2; o[3] = t3; o[4] = t4;
  }
}

// ---- transposed kmeans path (featsN stored fp16) ----

// float4 global reads, LDS transpose, fp16 (uint2 = 4 halves) writes.
__global__ void __launch_bounds__(256)
k_normT(const float4* __restrict__ feats4, uint2* __restrict__ featsH2, int N, int Z3) {
  __shared__ float xl[128 * 33];
  __shared__ float sinv[128];
  int tid = threadIdx.x;
  int nchunk = N >> 7;
  int Z3q = Z3 >> 2;
  for (int chunk = blockIdx.x; chunk < nchunk; chunk += gridDim.x) {
    int n0 = chunk << 7;
    int b = n0 / Z3, v0 = n0 - b * Z3;  // Z3 % 128 == 0: chunk within one b
    const float4* fb4 = feats4 + (size_t)b * DD * Z3q + (v0 >> 2);
#pragma unroll
    for (int j = 0; j < 4; ++j) {
      int idx = j * 256 + tid;          // 0..1023 float4 slots
      int d = idx >> 5, v4 = idx & 31;  // 32 float4 per d-row (128 floats)
      float4 f = fb4[(size_t)d * Z3q + v4];
      int vb = v4 << 2;
      xl[(vb + 0) * 33 + d] = f.x;
      xl[(vb + 1) * 33 + d] = f.y;
      xl[(vb + 2) * 33 + d] = f.z;
      xl[(vb + 3) * 33 + d] = f.w;
    }
    __syncthreads();
    if (tid < 128) {
      float s = 0.f;
#pragma unroll
      for (int d = 0; d < DD; ++d) { float x = xl[tid * 33 + d]; s += x * x; }
      sinv[tid] = 1.0f / sqrtf(s + 1e-12f);
    }
    __syncthreads();
#pragma unroll
    for (int j = 0; j < 4; ++j) {
      int idx = j * 256 + tid;
      int vox = idx >> 3, q = idx & 7;
      float iv = sinv[vox];
      float4 o;
      o.x = xl[vox * 33 + q * 4 + 0] * iv;
      o.y = xl[vox * 33 + q * 4 + 1] * iv;
      o.z = xl[vox * 33 + q * 4 + 2] * iv;
      o.w = xl[vox * 33 + q * 4 + 3] * iv;
      featsH2[(size_t)n0 * 8 + idx] = f4toh8(o);
    }
    __syncthreads();
  }
}

__global__ void k_initcentT(const u32* __restrict__ featsH,
                            const u64* __restrict__ top5F, float* __restrict__ cent, int N) {
  int t = threadIdx.x;
  if (t >= LBN * KMX * DD) return;
  int d = t & 31;
  int k = (t >> 5) % KMX;
  int i = t / (KMX * DD);
  u32 n = ~(u32)(top5F[(size_t)i * 5 + k]);
  if (n >= (u32)N) n = 0;
  const __half* fh = (const __half*)featsH;
  cent[(i * KMX + k) * DD + d] = __half2float(fh[(size_t)n * DD + d]);
}

// assignment v2: LDS float atomics (ds_add_f32) replace the 4-phase masked RMW.
// One accumulator copy per wave (4 copies) -> deterministic per-block order,
// ~15 KB LDS, no serial read-modify-write chains.
__global__ void __launch_bounds__(256)
k_assignW2(const uint2* __restrict__ featsH2, const u8* __restrict__ ci8,
           const float* __restrict__ cent, float* __restrict__ part, int N, int NB) {
  __shared__ float sc[LBN * KMX * SCPAD];
  __shared__ float ssw[4][LBN * KMX * SCPAD];
  __shared__ float scn[LBN * KMX];
  __shared__ float scw[4][LBN * KMX];
  int tid = threadIdx.x;
  for (int t = tid; t < LBN * KMX * DD; t += 256) {
    int cl2 = t >> 5, d = t & 31;
    sc[cl2 * SCPAD + d] = cent[t];
  }
  for (int t = tid; t < 4 * LBN * KMX * SCPAD; t += 256) (&ssw[0][0])[t] = 0.f;
  for (int t = tid; t < 4 * LBN * KMX; t += 256) (&scw[0][0])[t] = 0.f;
  __syncthreads();
  if (tid < LBN * KMX) {
    float s = 0.f;
#pragma unroll
    for (int d = 0; d < DD; ++d) { float c = sc[tid * SCPAD + d]; s += c * c; }
    scn[tid] = s;
  }
  __syncthreads();
  int q = tid & 7;
  int wv = tid >> 6;
  float* myss = &ssw[wv][0];
  float* mysc = &scw[wv][0];
  const float* scq = sc + q * 4;
  int nchunk = N >> 5;
  int chunk = blockIdx.x;
  if (chunk < nchunk) {
    uint2 h2 = featsH2[(size_t)chunk * 256 + tid];
    int cv = ci8[(chunk << 5) + (tid >> 3)];
    while (true) {
      int nxt = chunk + gridDim.x;
      bool has = nxt < nchunk;
      uint2 nh2 = make_uint2(0u, 0u); int ncv = 255;
      if (has) {
        nh2 = featsH2[(size_t)nxt * 256 + tid];
        ncv = ci8[(nxt << 5) + (tid >> 3)];
      }
      float4 f4 = h8tof4(h2);
      int ci = (cv == 255) ? -1 : cv;
      int basec = (ci < 0 ? 0 : ci) * KMX;
      float4 c0 = *(const float4*)(scq + (basec + 0) * SCPAD);
      float4 c1 = *(const float4*)(scq + (basec + 1) * SCPAD);
      float4 c2 = *(const float4*)(scq + (basec + 2) * SCPAD);
      float4 c3 = *(const float4*)(scq + (basec + 3) * SCPAD);
      float4 c4 = *(const float4*)(scq + (basec + 4) * SCPAD);
      float p0 = f4.x * c0.x + f4.y * c0.y + f4.z * c0.z + f4.w * c0.w;
      float p1 = f4.x * c1.x + f4.y * c1.y + f4.z * c1.z + f4.w * c1.w;
      float p2 = f4.x * c2.x + f4.y * c2.y + f4.z * c2.z + f4.w * c2.w;
      float p3 = f4.x * c3.x + f4.y * c3.y + f4.z * c3.z + f4.w * c3.w;
      float p4 = f4.x * c4.x + f4.y * c4.y + f4.z * c4.z + f4.w * c4.w;
#pragma unroll
      for (int o = 1; o < 8; o <<= 1) {
        p0 += __shfl_xor(p0, o, 64);
        p1 += __shfl_xor(p1, o, 64);
        p2 += __shfl_xor(p2, o, 64);
        p3 += __shfl_xor(p3, o, 64);
        p4 += __shfl_xor(p4, o, 64);
      }
      float bd = scn[basec + 0] - 2.0f * p0; int bk = 0;
      float d2;
      d2 = scn[basec + 1] - 2.0f * p1; if (d2 < bd) { bd = d2; bk = 1; }
      d2 = scn[basec + 2] - 2.0f * p2; if (d2 < bd) { bd = d2; bk = 2; }
      d2 = scn[basec + 3] - 2.0f * p3; if (d2 < bd) { bd = d2; bk = 3; }
      d2 = scn[basec + 4] - 2.0f * p4; if (d2 < bd) { bd = d2; bk = 4; }
      int cl = basec + bk;
      if (ci >= 0) {
        float* dst = myss + cl * SCPAD + q * 4;
        atomicAdd(dst + 0, f4.x);
        atomicAdd(dst + 1, f4.y);
        atomicAdd(dst + 2, f4.z);
        atomicAdd(dst + 3, f4.w);
        if (q == 0) atomicAdd(mysc + cl, 1.0f);
      }
      if (!has) break;
      chunk = nxt; h2 = nh2; cv = ncv;
    }
  }
  __syncthreads();
  // part transposed: part[p][block] -> coalesced reads in redupd
  for (int p = tid; p < 660; p += 256) {
    float v;
    if (p < 640) {
      int idx = (p >> 5) * SCPAD + (p & 31);
      v = ssw[0][idx] + ssw[1][idx] + ssw[2][idx] + ssw[3][idx];
    } else {
      int ik = p - 640;
      v = scw[0][ik] + scw[1][ik] + scw[2][ik] + scw[3][ik];
    }
    part[(size_t)p * NB + blockIdx.x] = v;
  }
}

// reduce + centroid update; empty clusters flag emptyMask (fixed by k_fixempty)
__global__ void k_redupdT(const float* __restrict__ part, float* __restrict__ cent,
                          float* __restrict__ sums, float* __restrict__ kcnt,
                          u32* __restrict__ emptyMask, int NB) {
  __shared__ float w4[8];
  int p = blockIdx.x;
  int tid = threadIdx.x;  // 256
  if (p < 640) {
    int ik = p >> 5;
    float s = 0.f, c = 0.f;
    for (int b2 = tid; b2 < NB; b2 += 256) {
      s += part[(size_t)p * NB + b2];
      c += part[(size_t)(640 + ik) * NB + b2];
    }
    s = rsum64(s); c = rsum64(c);
    int wid = tid >> 6;
    if ((tid & 63) == 0) { w4[wid] = s; w4[4 + wid] = c; }
    __syncthreads();
    if (tid == 0) {
      float S = w4[0] + w4[1] + w4[2] + w4[3];
      float C = w4[4] + w4[5] + w4[6] + w4[7];
      sums[p] = S;
      if (C > 0.f) cent[p] = S / fmaxf(C, 1.0f);
      else atomicOr(emptyMask, 1u << ik);
    }
  } else if (p < 660) {
    int ik = p - 640;
    float c = 0.f;
    for (int b2 = tid; b2 < NB; b2 += 256) c += part[(size_t)(640 + ik) * NB + b2];
    c = rsum64(c);
    int wid = tid >> 6;
    if ((tid & 63) == 0) w4[wid] = c;
    __syncthreads();
    if (tid == 0) kcnt[ik] = w4[0] + w4[1] + w4[2] + w4[3];
  }
}

// gated: exact fallback top-5 for empty clusters (runs only if emptyMask != 0)
__global__ void __launch_bounds__(1024)
k_fixempty(const u32* __restrict__ featsH, const int* __restrict__ gt,
           const int* __restrict__ labeled, RKeys RK, u32* __restrict__ emptyMask,
           float* __restrict__ cent, int iter, int N) {
  u32 mask = emptyMask[0];
  if (mask == 0u) return;
  __shared__ u64 wbuf[16 * 5];
  __shared__ u32 idxs[KMX];
  int tid = threadIdx.x;
  u32 halfF = (u32)(((u64)5 * (u64)N) / 2);
  for (int ci = 0; ci < LBN; ++ci) {
    if (((mask >> (ci * KMX)) & 0x1Fu) == 0u) continue;
    int c = labeled[ci];
    u32 fa = RK.kf[ci][0], fb = RK.kf[ci][1];
    u32 base = (u32)iter * (u32)N;
    u64 t0 = 0, t1 = 0, t2 = 0, t3 = 0, t4 = 0;
    for (int n = tid; n < N; n += 1024) {
      if (gt[n] != c) continue;
      u32 uk = jax_ukey(fa, fb, halfF, base + (u32)n);
      u64 key = ((u64)uk << 32) | (u32)(~(u32)n);
      INS5(key, t0, t1, t2, t3, t4);
    }
    WMERGE_ALL(t0, t1, t2, t3, t4);
    int wid = tid >> 6;
    if ((tid & 63) == 0) {
      wbuf[wid * 5 + 0] = t0; wbuf[wid * 5 + 1] = t1; wbuf[wid * 5 + 2] = t2;
      wbuf[wid * 5 + 3] = t3; wbuf[wid * 5 + 4] = t4;
    }
    __syncthreads();
    if (tid == 0) {
      for (int w = 1; w < 16; ++w)
        for (int j = 0; j < 5; ++j) { u64 k = wbuf[w * 5 + j]; INS5(k, t0, t1, t2, t3, t4); }
      idxs[0] = ~(u32)t0; idxs[1] = ~(u32)t1; idxs[2] = ~(u32)t2;
      idxs[3] = ~(u32)t3; idxs[4] = ~(u32)t4;
    }
    __syncthreads();
    if (tid < KMX * DD) {
      int k = tid >> 5, d = tid & 31;
      if ((mask >> (ci * KMX + k)) & 1u) {
        u32 n = idxs[k];
        if (n >= (u32)N) n = 0;
        const __half* fh = (const __half*)featsH;
        cent[(ci * KMX + k) * DD + d] = __half2float(fh[(size_t)n * DD + d]);
      }
    }
    __syncthreads();
  }
  if (tid == 0) emptyMask[0] = 0u;
}

__global__ void k_prepT(const uint2* __restrict__ featsH2,
                        const int* __restrict__ pseudo, const SelState* __restrict__ st,
                        const int* __restrict__ aidx, float4* __restrict__ afe4,
                        int* __restrict__ alab, int N) {
  int tid = threadIdx.x;
  int r = blockIdx.x * 32 + (tid >> 3);
  int q = tid & 7;
  if (r >= (int)st->target) return;
  int n = aidx[r];
  if ((u32)n >= (u32)N) n = 0;
  if (q == 0) {
    int lb = pseudo[n];
    alab[r] = lb < 0 ? 0 : (lb > NCLS - 1 ? NCLS - 1 : lb);
  }
  afe4[(size_t)r * 8 + q] = h8tof4(featsH2[(size_t)n * 8 + q]);
}

// ---- anchor selection: one-pass prefilter + parallel rank-count; gated radix rescue ----

__global__ void __launch_bounds__(256)
k_anchsel(const int* __restrict__ pseudo, RKeys RK, u64* __restrict__ cand4k,
          SelState* st, int N) {
  __shared__ u32 mcnt[4];
  u32 K0 = RK.k1000[0], K1 = RK.k1000[1];
  u32 half = (u32)(N / 2);
  int tid = threadIdx.x;
  int lcnt = 0;
  int stride = gridDim.x * blockDim.x;
  for (int n = blockIdx.x * blockDim.x + tid; n < N; n += stride) {
    bool valid = pseudo[n] > 0;
    lcnt += valid ? 1 : 0;
    u32 uk = jax_ukey(K0, K1, half, (u32)n);
    bool c = valid && (uk >= UKTHR);
    if (__ballot(c)) {
      if (c) {
        u32 p = atomicAdd(&st->ncand, 1u);
        if (p < (u32)ACAP) cand4k[p] = ((u64)uk << 32) | (u32)(~(u32)n);
      }
    }
  }
#pragma unroll
  for (int o = 32; o; o >>= 1) lcnt += __shfl_xor(lcnt, o, 64);
  if ((tid & 63) == 0) mcnt[tid >> 6] = (u32)lcnt;
  __syncthreads();
  if (tid == 0) atomicAdd(&st->M, mcnt[0] + mcnt[1] + mcnt[2] + mcnt[3]);
}

__global__ void k_selmode(SelState* st, u32* rescue) {
  if (threadIdx.x != 0 || blockIdx.x != 0) return;
  u32 M = st->M;
  u32 tgt = M < (u32)MAXA ? M : (u32)MAXA;
  st->target = tgt;
  if (!(st->ncand >= tgt && st->ncand <= (u32)ACAP)) rescue[1] = 1u;
}

__global__ void __launch_bounds__(256)
k_rank(const u64* __restrict__ cand4k, const SelState* __restrict__ st,
       const u32* __restrict__ rescue, int* __restrict__ aidx) {
  if (rescue[1]) return;
  __shared__ u64 keys[ACAP];
  u32 nc = st->ncand; if (nc > (u32)ACAP) nc = (u32)ACAP;
  u32 target = st->target;
  int tid = threadIdx.x;
  for (int t = tid; t < ACAP; t += 256) keys[t] = (t < (int)nc) ? cand4k[t] : 0ULL;
  __syncthreads();
  int i = blockIdx.x * 256 + tid;
  if (i >= (int)nc) return;
  u64 my = keys[i];
  u32 rank = 0;
  for (u32 j = 0; j < nc; ++j) rank += (keys[j] > my) ? 1u : 0u;
  if (rank < target) aidx[rank] = (int)(~(u32)my);
}

// -- gated radix rescue chain --

__global__ void k_svinit(const int* __restrict__ pseudo, RKeys RK, const u32* __restrict__ rescue,
                         u32* __restrict__ sv, u32* __restrict__ hist, int N) {
  if (!rescue[1]) return;
  __shared__ u32 h[2048];
  for (int t = threadIdx.x; t < 2048; t += blockDim.x) h[t] = 0;
  __syncthreads();
  u32 half = (u32)(N / 2);
  u32 K0 = RK.k1000[0], K1 = RK.k1000[1];
  int Nq = N >> 2;
  int stride = gridDim.x * blockDim.x;
  for (int q = blockIdx.x * blockDim.x + threadIdx.x; q < Nq; q += stride) {
    int4 p4 = ((const int4*)pseudo)[q];
    int n = q << 2;
    u32 s0 = 0, s1 = 0, s2 = 0, s3 = 0;
    if (p4.x > 0) { s0 = jax_ukey(K0, K1, half, (u32)n);     atomicAdd(&h[s0 >> 21], 1u); }
    if (p4.y > 0) { s1 = jax_ukey(K0, K1, half, (u32)n + 1); atomicAdd(&h[s1 >> 21], 1u); }
    if (p4.z > 0) { s2 = jax_ukey(K0, K1, half, (u32)n + 2); atomicAdd(&h[s2 >> 21], 1u); }
    if (p4.w > 0) { s3 = jax_ukey(K0, K1, half, (u32)n + 3); atomicAdd(&h[s3 >> 21], 1u); }
    ((uint4*)sv)[q] = make_uint4(s0, s1, s2, s3);
  }
  __syncthreads();
  for (int t = threadIdx.x; t < 2048; t += blockDim.x) if (h[t]) atomicAdd(&hist[t], h[t]);
}

__global__ void k_hist12(const u32* __restrict__ sv, u32* __restrict__ hist,
                         const SelState* __restrict__ st, const u32* __restrict__ rescue,
                         int pass, int N) {
  if (!rescue[1]) return;
  __shared__ u32 h[2048];
  for (int t = threadIdx.x; t < 2048; t += blockDim.x) h[t] = 0;
  __syncthreads();
  u32 pre = (pass == 1) ? st->prefix1 : st->prefix21;
  int Nq = N >> 2;
  int stride = gridDim.x * blockDim.x;
  for (int q = blockIdx.x * blockDim.x + threadIdx.x; q < Nq; q += stride) {
    uint4 s4 = ((const uint4*)sv)[q];
#define H12(s_) do { u32 s = (s_); if (s) { \
      if (pass == 1) { if ((s >> 21) == pre) atomicAdd(&h[(s >> 10) & 0x7FFu], 1u); } \
      else           { if ((s >> 10) == pre) atomicAdd(&h[s & 0x3FFu], 1u); } } } while (0)
    H12(s4.x); H12(s4.y); H12(s4.z); H12(s4.w);
#undef H12
  }
  __syncthreads();
  for (int t = threadIdx.x; t < 2048; t += blockDim.x) if (h[t]) atomicAdd(&hist[t], h[t]);
}

__global__ void k_scan(const u32* __restrict__ hist, SelState* st,
                       const u32* __restrict__ rescue, int pass) {
  if (!rescue[1]) return;
  __shared__ u32 h[2048];
  __shared__ u32 csum[256];
  __shared__ u32 sh_rank;
  __shared__ int sh_found;
  __shared__ u32 sh_rem;
  int tid = threadIdx.x;  // 256
  int nb = (pass == 2) ? 1024 : 2048;
  for (int t = tid; t < 2048; t += 256) h[t] = (t < nb) ? hist[t] : 0u;
  __syncthreads();
  u32 cs = 0;
#pragma unroll
  for (int j = 0; j < 8; ++j) cs += h[tid * 8 + j];
  csum[tid] = cs;
  __syncthreads();
  if (tid == 0) {
    sh_rank = (pass == 0) ? st->target : (pass == 1 ? st->rank1 : st->rank2);
    sh_found = -1;
    sh_rem = 0;
  }
  __syncthreads();
  u32 rank = sh_rank;
  if (rank > 0) {
    u32 above = 0;
    for (int j = tid + 1; j < 256; ++j) above += csum[j];
    u32 run = above;
    for (int b = tid * 8 + 7; b >= tid * 8; --b) {
      u32 c = h[b];
      if (run < rank && rank <= run + c) { sh_found = b; sh_rem = rank - run; }
      run += c;
    }
  }
  __syncthreads();
  if (tid == 0) {
    int found = sh_found;
    u32 rem = sh_rem;
    if (pass == 0) {
      if (found < 0) { st->prefix1 = 0xFFFFFFFFu; st->rank1 = 0; }
      else { st->prefix1 = (u32)found; st->rank1 = rem; }
    } else if (pass == 1) {
      if (found < 0) { st->prefix21 = 0xFFFFFFFFu; st->rank2 = 0; }
      else { st->prefix21 = (st->prefix1 << 11) | (u32)found; st->rank2 = rem; }
    } else {
      if (found < 0) st->pivot_sv = 0xFFFFFFFFu;
      else st->pivot_sv = (st->prefix21 << 10) | (u32)found;
    }
  }
}

__global__ void k_gather(const u32* __restrict__ sv, SelState* st,
                         const u32* __restrict__ rescue, u64* __restrict__ cand, int N) {
  if (!rescue[1]) return;
  if (st->target == 0) return;
  u32 piv = st->pivot_sv;
  int Nq = N >> 2;
  int stride = gridDim.x * blockDim.x;
  for (int q = blockIdx.x * blockDim.x + threadIdx.x; q < Nq; q += stride) {
    uint4 s4 = ((const uint4*)sv)[q];
    int n = q << 2;
#define GPUSH(s_, nn_) do { u32 s = (s_); \
    if (s && s >= piv) { u32 p = atomicAdd(&st->ncand2, 1u); \
      if (p < 4096u) cand[p] = ((u64)s << 32) | (u32)(~(u32)(nn_)); } } while (0)
    GPUSH(s4.x, n); GPUSH(s4.y, n + 1); GPUSH(s4.z, n + 2); GPUSH(s4.w, n + 3);
#undef GPUSH
  }
}

__global__ void __launch_bounds__(1024) k_sortsel(const u64* __restrict__ cand,
                                                  const SelState* __restrict__ st,
                                                  const u32* __restrict__ rescue,
                                                  int* __restrict__ aidx) {
  if (!rescue[1]) return;
  __shared__ u64 s[4096];
  u32 nc = st->ncand2; if (nc > 4096u) nc = 4096u;
  u32 target = st->target;
  for (int t = threadIdx.x; t < 4096; t += blockDim.x) s[t] = (t < (int)nc) ? cand[t] : 0ULL;
  __syncthreads();
  for (u32 ksz = 2; ksz <= 4096; ksz <<= 1) {
    for (u32 j = ksz >> 1; j > 0; j >>= 1) {
      for (u32 idx = threadIdx.x; idx < 4096; idx += blockDim.x) {
        u32 ixj = idx ^ j;
        if (ixj > idx) {
          bool up = (idx & ksz) == 0;
          u64 A = s[idx], B = s[ixj];
          bool sw = up ? (A < B) : (A > B);
          if (sw) { s[idx] = B; s[ixj] = A; }
        }
      }
      __syncthreads();
    }
  }
  for (int t = threadIdx.x; t < MAXA; t += blockDim.x)
    if (t < (int)target) aidx[t] = (int)(~(u32)s[t]);
}

// ---- shared tail ----

__global__ void k_anchor_final(const float* __restrict__ cent, const float* __restrict__ sums,
                               const float* __restrict__ kcnt, const float* __restrict__ protn,
                               const int* __restrict__ labeled, float* __restrict__ accum) {
  int i = blockIdx.x;
  int d = threadIdx.x;
  if (d >= DD) return;
  int c = labeled[i];
  float cnt = 0.f;
#pragma unroll
  for (int k = 0; k < KMX; ++k) cnt += kcnt[i * KMX + k];
  int cs = c < 0 ? 0 : (c > NCLS - 1 ? NCLS - 1 : c);
  float part = 0.f;
  if (cnt >= (float)KMX) {
#pragma unroll
    for (int k = 0; k < KMX; ++k) {
      float v = cent[(i * KMX + k) * DD + d];
      float s = rsum32(v * v);
      float dn1 = sqrtf(s + 1e-12f);
      float v1 = v / dn1;
      float s2 = rsum32(v1 * v1);
      float dn2 = sqrtf(s2 + 1e-12f);
      float vv = v1 / dn2;
      float df = protn[(cs * KMX + k) * DD + d] - vv;
      part += df * df;
    }
  } else {
    float mv = 0.f;
#pragma unroll
    for (int k = 0; k < KMX; ++k) mv += sums[(i * KMX + k) * DD + d];
    mv /= fmaxf(cnt, 1.0f);
    float s = rsum32(mv * mv);
    float dn = sqrtf(s + 1e-12f);
    float vv = mv / dn;
#pragma unroll
    for (int k = 0; k < KMX; ++k) {
      float df = protn[(cs * KMX + k) * DD + d] - vv;
      part += df * df;
    }
  }
  float ls = rsum32(part) * (1.0f / (KMX * DD));
  bool valid = (c != 0) && (c < NCLS) && (cnt > 0.f);
  if (d == 0 && valid) { atomicAdd(&accum[0], ls); atomicAdd(&accum[1], 1.0f); }
}

__global__ void k_triplet(const float* __restrict__ protn, const float* __restrict__ afe,
                          const int* __restrict__ alab, const SelState* __restrict__ st,
                          RKeys RK, float* __restrict__ acc) {
  __shared__ float pn[CKK * DD];
  __shared__ float spn[CKK];
  int tid = threadIdx.x;
  for (int t = tid; t < CKK * DD; t += blockDim.x) pn[t] = protn[t];
  __syncthreads();
  if (tid < CKK) {
    float s = 0.f;
    for (int d = 0; d < DD; ++d) s += pn[tid * DD + d] * pn[tid * DD + d];
    spn[tid] = s;
  }
  __syncthreads();
  int r = blockIdx.x * blockDim.x + tid;
  if (r >= (int)st->target) return;
  float a[DD]; float sa = 0.f;
#pragma unroll
  for (int d = 0; d < DD; ++d) { a[d] = afe[(size_t)r * DD + d]; sa += a[d] * a[d]; }
  int lab = alab[r];
  int ob = lab * KMX;
  float bs = -3.4e38f; int pidx = ob;
  float pos_d = 3.4e38f;
  for (int k = ob; k < ob + KMX; ++k) {
    float dot = 0.f;
#pragma unroll
    for (int d = 0; d < DD; ++d) dot += a[d] * pn[k * DD + d];
    if (dot > bs) { bs = dot; pidx = k; }
    float d2 = (sa + spn[k]) - 2.0f * dot;
    float dd = sqrtf(fmaxf(d2, 0.f));
    pos_d = fminf(pos_d, dd);
  }
  u32 halfT = (u32)(MAXA * CKK / 2);
  bool any_semi = false;
  u32 bu1 = 0; int k1i = 0;
  u32 bu2 = 0; int k2i = 0;
  for (int k = 0; k < CKK; ++k) {
    if (k / KMX == lab) continue;
    float dot = 0.f;
#pragma unroll
    for (int d = 0; d < DD; ++d) dot += a[d] * pn[k * DD + d];
    float d2 = (sa + spn[k]) - 2.0f * dot;
    float dd = sqrtf(fmaxf(d2, 0.f));
    u32 j = (u32)(r * CKK + k);
    bool semi = (dd > pos_d) && (dd < pos_d + 1.0f);
    if (semi) {
      u32 u1 = jax_ukey(RK.k2000[0], RK.k2000[1], halfT, j);
      any_semi = true;
      if (u1 > bu1) { bu1 = u1; k1i = k; }
    }
    u32 u2 = jax_ukey(RK.k2001[0], RK.k2001[1], halfT, j);
    if (u2 > bu2) { bu2 = u2; k2i = k; }
  }
  int nidx = any_semi ? k1i : k2i;
  float aden = sqrtf(sa + 1e-12f);
  float pden = sqrtf(spn[pidx] + 1e-12f);
  float nden = sqrtf(spn[nidx] + 1e-12f);
  float s1 = 0.f, s2 = 0.f;
#pragma unroll
  for (int d = 0; d < DD; ++d) {
    float an = a[d] / aden;
    float pv = pn[pidx * DD + d] / pden;
    float nv = pn[nidx * DD + d] / nden;
    float t1 = an - pv; s1 += t1 * t1;
    float t2 = an - nv; s2 += t2 * t2;
  }
  float d_pos = sqrtf(s1 + 1e-12f);
  float d_neg = sqrtf(s2 + 1e-12f);
  float xx = (d_pos - d_neg) + 1.0f;
  float l = fmaxf(xx, 0.f) + log1pf(expf(-fabsf(xx)));
  atomicAdd(&acc[0], l);
  atomicAdd(&acc[1], 1.0f);
}

__global__ void k_final(const float* __restrict__ anchor_acc, const float* __restrict__ proto_acc,
                        const float* __restrict__ compact, float* __restrict__ out) {
  if (threadIdx.x != 0 || blockIdx.x != 0) return;
  float al = anchor_acc[0] / fmaxf(anchor_acc[1], 1.0f);
  float pl = proto_acc[0] / fmaxf(proto_acc[1], 1.0f);
  out[0] = pl + 1.0f * al + 0.1f * compact[0];
}

// ---------------- host ----------------

static void host_keys(RKeys* K) {
  const u32 b0 = 0u, b1 = 42u;
  u32 o0, o1;
  for (int i = 0; i < LBN; ++i) {
    u32 f0, f1;
    tf2x32(b0, b1, 0u, (u32)i, &f0, &f1);
    u32 p0, q0, p1, q1;
    tf2x32(f0, f1, 0u, 2u, &p0, &q0);
    tf2x32(f0, f1, 1u, 3u, &p1, &q1);
    K->ki[i][0] = p0; K->ki[i][1] = p1;
    K->kf[i][0] = q0; K->kf[i][1] = q1;
  }
  tf2x32(b0, b1, 0u, 1000u, &o0, &o1); K->k1000[0] = o0; K->k1000[1] = o1;
  tf2x32(b0, b1, 0u, 2000u, &o0, &o1); K->k2000[0] = o0; K->k2000[1] = o1;
  tf2x32(b0, b1, 0u, 2001u, &o0, &o1); K->k2001[0] = o0; K->k2001[1] = o1;
}

extern "C" void kernel_launch(void* const* d_in, const int* in_sizes, int n_in,
                              void* d_out, int out_size, void* d_ws, size_t ws_size,
                              hipStream_t stream) {
  const float* feats = (const float*)d_in[0];
  const float* protos = (const float*)d_in[1];
  const int* pseudo = (const int*)d_in[2];
  const int* gt = (const int*)d_in[3];
  const int* labeled = (const int*)d_in[4];
  float* out = (float*)d_out;

  int N = in_sizes[2];
  int Z3 = N / 4;

  RKeys RK;
  host_keys(&RK);

  const int nbas[3] = {1536, 768, 384};
  for (int attempt = 0; attempt < 3; ++attempt) {
    int NBAS = nbas[attempt];
    char* W = (char*)d_ws;
    size_t off = 0;
    auto alloc = [&](size_t bytes) -> char* {
      char* p = W + off;
      off += (bytes + 255) & ~(size_t)255;
      return p;
    };
    char* zeroBase = W + off;
    u32* hist3 = (u32*)alloc(3 * 2048 * 4);
    SelState* st = (SelState*)alloc(256);
    float* anchor_acc = (float*)alloc(256);
    float* proto_acc = (float*)alloc(256);
    u32* rescue = (u32*)alloc(256);  // [0]=top5 class mask, [1]=anchor rescue, [2]=emptyMask
    size_t zeroBytes = (size_t)((W + off) - zeroBase);
    u64* cand4k = (u64*)alloc((size_t)ACAP * 8);
    u64* outA = (u64*)alloc((size_t)LBN * NBLKA * 5 * 8);
    u64* top5F = (u64*)alloc((size_t)LBN * 5 * 8);
    float* cent = (float*)alloc((size_t)LBN * KMX * DD * 4);
    float* sums = (float*)alloc((size_t)LBN * KMX * DD * 4);
    float* kcnt = (float*)alloc((size_t)LBN * KMX * 4);
    float* protn = (float*)alloc((size_t)CKK * DD * 4);
    float* compact = (float*)alloc(256);
    u32* sv = (u32*)alloc((size_t)N * 4);
    float* part = (float*)alloc((size_t)680 * NBAS * 4);
    u64* cand = (u64*)alloc(4096 * 8);
    int* aidx = (int*)alloc((size_t)MAXA * 4);
    int* alab = (int*)alloc((size_t)MAXA * 4);
    float* afe = (float*)alloc((size_t)MAXA * DD * 4);
    u32* featsH = (u32*)alloc((size_t)N * DD * 2);  // fp16 normalized features
    u8* ci8 = (u8*)alloc((size_t)N);                // per-voxel class index
    if (ws_size < off) continue;

    hipMemsetAsync(zeroBase, 0, zeroBytes, stream);

    k_protos<<<dim3(1), dim3(256), 0, stream>>>(protos, protn, compact);

    // top-5 init selection (kind 0 only) + ci8 materialization; gated exact rescue
    k_top5A<<<dim3(NBLKA), dim3(256), 0, stream>>>(gt, labeled, RK, outA, ci8, N);
    k_top5B<<<dim3(LBN), dim3(256), 0, stream>>>(outA, rescue, top5F, NBLKA);
    k_top5A_resc<<<dim3(NBLKA), dim3(256), 0, stream>>>(gt, labeled, RK, rescue, outA, N);
    k_top5B_resc<<<dim3(LBN), dim3(256), 0, stream>>>(outA, rescue, top5F, NBLKA);

    uint2* featsH2 = (uint2*)featsH;
    k_normT<<<dim3(4096), dim3(256), 0, stream>>>((const float4*)feats, featsH2, N, Z3);
    k_initcentT<<<dim3(1), dim3(LBN * KMX * DD), 0, stream>>>(featsH, top5F, cent, N);
    for (int it = 0; it < KIT; ++it) {
      k_assignW2<<<dim3(NBAS), dim3(256), 0, stream>>>(featsH2, ci8, cent, part, N, NBAS);
      k_redupdT<<<dim3(660), dim3(256), 0, stream>>>(part, cent, sums, kcnt, rescue + 2, NBAS);
      k_fixempty<<<dim3(1), dim3(1024), 0, stream>>>(featsH, gt, labeled, RK, rescue + 2, cent, it, N);
    }
    k_anchor_final<<<dim3(LBN), dim3(64), 0, stream>>>(cent, sums, kcnt, protn, labeled, anchor_acc);

    // anchor selection: one-pass prefilter; rank-count; gated radix rescue
    k_anchsel<<<dim3(2048), dim3(256), 0, stream>>>(pseudo, RK, cand4k, st, N);
    k_selmode<<<dim3(1), dim3(64), 0, stream>>>(st, rescue);
    k_svinit<<<dim3(1024), dim3(256), 0, stream>>>(pseudo, RK, rescue, sv, hist3, N);
    k_scan<<<dim3(1), dim3(256), 0, stream>>>(hist3, st, rescue, 0);
    k_hist12<<<dim3(1024), dim3(256), 0, stream>>>(sv, hist3 + 2048, st, rescue, 1, N);
    k_scan<<<dim3(1), dim3(256), 0, stream>>>(hist3 + 2048, st, rescue, 1);
    k_hist12<<<dim3(1024), dim3(256), 0, stream>>>(sv, hist3 + 4096, st, rescue, 2, N);
    k_scan<<<dim3(1), dim3(256), 0, stream>>>(hist3 + 4096, st, rescue, 2);
    k_gather<<<dim3(1024), dim3(256), 0, stream>>>(sv, st, rescue, cand, N);
    k_sortsel<<<dim3(1), dim3(1024), 0, stream>>>(cand, st, rescue, aidx);
    k_rank<<<dim3(ACAP / 256), dim3(256), 0, stream>>>(cand4k, st, rescue, aidx);

    k_prepT<<<dim3(MAXA / 32), dim3(256), 0, stream>>>(featsH2, pseudo, st, aidx,
                                                        (float4*)afe, alab, N);
    k_triplet<<<dim3(MAXA / 256), dim3(256), 0, stream>>>(protn, afe, alab, st, RK, proto_acc);

    k_final<<<dim3(1), dim3(64), 0, stream>>>(anchor_acc, proto_acc, compact, out);
    return;
  }
}

// Round 22
// 555.216 us; speedup vs baseline: 2.0529x; 2.0529x over previous
//
#include <hip/hip_runtime.h>
#include <hip/hip_fp16.h>
#include <stdint.h>

typedef unsigned int u32;
typedef unsigned long long u64;
typedef unsigned char u8;

#define NCLS 5
#define KMX 5
#define DD 32
#define LBN 4
#define KIT 5
#define MAXA 2048
#define CKK 25
#define NBLKA 256
#define SCPAD 36
#define ACAP 4096
#define UKTHR ((1u << 23) + 1u - (1u << 15))

struct RKeys {
  u32 ki[LBN][2];
  u32 kf[LBN][2];
  u32 k1000[2];
  u32 k2000[2];
  u32 k2001[2];
};

struct SelState {
  u32 prefix1, rank1, prefix21, rank2, pivot_sv, target, M, ncand, ncand2;
};

// ---------------- threefry2x32 (bit-exact JAX) ----------------
__host__ __device__ inline void tf2x32(u32 k0, u32 k1, u32 x0, u32 x1, u32* o0, u32* o1) {
  u32 ks2 = k0 ^ k1 ^ 0x1BD11BDAu;
  u32 ks[3] = {k0, k1, ks2};
  x0 += k0; x1 += k1;
  const int rotA[4] = {13, 15, 26, 6};
  const int rotB[4] = {17, 29, 16, 24};
#pragma unroll
  for (int g = 0; g < 5; ++g) {
#pragma unroll
    for (int j = 0; j < 4; ++j) {
      int r = (g & 1) ? rotB[j] : rotA[j];
      x0 += x1;
      x1 = (x1 << r) | (x1 >> (32 - r));
      x1 ^= x0;
    }
    x0 += ks[(g + 1) % 3];
    x1 += ks[(g + 2) % 3] + (u32)(g + 1);
  }
  *o0 = x0; *o1 = x1;
}

// Monotone surrogate key for JAX gumbel (order-preserving; 0 = invalid).
__device__ inline u32 jax_ukey(u32 k0, u32 k1, u32 half, u32 idx) {
  bool hi = (idx >= half);
  u32 c0 = hi ? (idx - half) : idx;
  u32 c1 = hi ? idx : (idx + half);
  u32 o0, o1;
  tf2x32(k0, k1, c0, c1, &o0, &o1);
  u32 bits = hi ? o1 : o0;
  return (bits >> 9) + 1u;
}

#define INS5(kk, a0, a1, a2, a3, a4) do { u64 _k = (kk); \
  if (_k > a4) { a4 = _k; u64 _t; \
    if (a4 > a3) { _t = a3; a3 = a4; a4 = _t; } \
    if (a3 > a2) { _t = a2; a2 = a3; a3 = _t; } \
    if (a2 > a1) { _t = a1; a1 = a2; a2 = _t; } \
    if (a1 > a0) { _t = a0; a0 = a1; a1 = _t; } } } while (0)

#define WMERGE5(off, a0, a1, a2, a3, a4) do { \
  u64 r0 = __shfl_xor(a0, off, 64), r1 = __shfl_xor(a1, off, 64), \
      r2 = __shfl_xor(a2, off, 64), r3 = __shfl_xor(a3, off, 64), \
      r4 = __shfl_xor(a4, off, 64); \
  INS5(r0, a0, a1, a2, a3, a4); INS5(r1, a0, a1, a2, a3, a4); \
  INS5(r2, a0, a1, a2, a3, a4); INS5(r3, a0, a1, a2, a3, a4); \
  INS5(r4, a0, a1, a2, a3, a4); } while (0)

#define WMERGE_ALL(a0,a1,a2,a3,a4) do { \
  WMERGE5(32,a0,a1,a2,a3,a4); WMERGE5(16,a0,a1,a2,a3,a4); WMERGE5(8,a0,a1,a2,a3,a4); \
  WMERGE5(4,a0,a1,a2,a3,a4); WMERGE5(2,a0,a1,a2,a3,a4); WMERGE5(1,a0,a1,a2,a3,a4); } while (0)

__device__ inline float rsum32(float v) {
#pragma unroll
  for (int o = 16; o; o >>= 1) v += __shfl_xor(v, o, 32);
  return v;
}

__device__ inline float rsum64(float v) {
#pragma unroll
  for (int o = 32; o; o >>= 1) v += __shfl_xor(v, o, 64);
  return v;
}

// fp16 pack/unpack: 4 halves in a uint2
__device__ inline float4 h8tof4(uint2 u) {
  __half2 a = *reinterpret_cast<__half2*>(&u.x);
  __half2 b = *reinterpret_cast<__half2*>(&u.y);
  float2 fa = __half22float2(a), fb = __half22float2(b);
  return make_float4(fa.x, fa.y, fb.x, fb.y);
}
__device__ inline uint2 f4toh8(float4 f) {
  __half2 a = __float22half2_rn(make_float2(f.x, f.y));
  __half2 b = __float22half2_rn(make_float2(f.z, f.w));
  uint2 u;
  u.x = *reinterpret_cast<u32*>(&a);
  u.y = *reinterpret_cast<u32*>(&b);
  return u;
}

// ---------------- kernels ----------------

__global__ void k_protos(const float* __restrict__ protos, float* __restrict__ protn, float* __restrict__ compact) {
  __shared__ float pl[CKK * DD];
  __shared__ float rn[CKK];
  __shared__ float red[4];
  int tid = threadIdx.x;  // 256
  for (int t = tid; t < CKK * DD; t += 256) pl[t] = protos[t];
  __syncthreads();
  if (tid < CKK) {
    float s = 0.f;
    for (int d = 0; d < DD; ++d) { float x = pl[tid * DD + d]; s += x * x; }
    rn[tid] = sqrtf(s + 1e-12f);
  }
  __syncthreads();
  for (int t = tid; t < CKK * DD; t += 256) {
    float v = pl[t] / rn[t / DD];
    pl[t] = v;
    protn[t] = v;
  }
  __syncthreads();
  float part = 0.f;
  if (tid < (NCLS - 1) * DD) {
    int c = 1 + tid / DD;
    int d = tid % DD;
    float m = 0.f;
#pragma unroll
    for (int k = 0; k < KMX; ++k) m += pl[(c * KMX + k) * DD + d];
    m *= (1.0f / KMX);
    float v = 0.f;
#pragma unroll
    for (int k = 0; k < KMX; ++k) { float df = pl[(c * KMX + k) * DD + d] - m; v += df * df; }
    part = v * (1.0f / (KMX - 1)) * (1.0f / DD);
  }
#pragma unroll
  for (int o = 32; o; o >>= 1) part += __shfl_xor(part, o, 64);
  int wid = tid >> 6;
  if ((tid & 63) == 0) red[wid] = part;
  __syncthreads();
  if (tid == 0) compact[0] = red[0] + red[1] + red[2] + red[3];
}

// ---- top-5 (kind 0 / init only): threshold-gated register scan + exact rescue ----
// Main pass also materializes ci8[n] (class index 0..3, 255 = unlabeled).

#define T5PROC_THR(gv_, nn_, cv_) do { \
  int ci = (gv_ == lb0) ? 0 : (gv_ == lb1) ? 1 : (gv_ == lb2) ? 2 : (gv_ == lb3) ? 3 : -1; \
  cv_ = (u8)(ci < 0 ? 255 : ci); \
  if (ci >= 0) { \
    u32 k0 = (ci & 2) ? ((ci & 1) ? ka3 : ka2) : ((ci & 1) ? ka1 : ka0); \
    u32 k1 = (ci & 2) ? ((ci & 1) ? kb3 : kb2) : ((ci & 1) ? kb1 : kb0); \
    u32 uk = jax_ukey(k0, k1, half, (u32)(nn_)); \
    if (uk >= UKTHR) { \
      u64 key = ((u64)uk << 32) | (u32)(~(u32)(nn_)); \
      if (ci == 0) { INS5(key, A0, A1, A2, A3, A4); } \
      else if (ci == 1) { INS5(key, B0, B1, B2, B3, B4); } \
      else if (ci == 2) { INS5(key, C0, C1, C2, C3, C4); } \
      else { INS5(key, D0, D1, D2, D3, D4); } \
    } \
  } } while (0)

#define T5PROC(gv_, nn_) do { \
  int ci = (gv_ == lb0) ? 0 : (gv_ == lb1) ? 1 : (gv_ == lb2) ? 2 : (gv_ == lb3) ? 3 : -1; \
  if (ci >= 0) { \
    u32 k0 = (ci & 2) ? ((ci & 1) ? ka3 : ka2) : ((ci & 1) ? ka1 : ka0); \
    u32 k1 = (ci & 2) ? ((ci & 1) ? kb3 : kb2) : ((ci & 1) ? kb1 : kb0); \
    u32 uk = jax_ukey(k0, k1, half, (u32)(nn_)); \
    u64 key = ((u64)uk << 32) | (u32)(~(u32)(nn_)); \
    if (ci == 0) { INS5(key, A0, A1, A2, A3, A4); } \
    else if (ci == 1) { INS5(key, B0, B1, B2, B3, B4); } \
    else if (ci == 2) { INS5(key, C0, C1, C2, C3, C4); } \
    else { INS5(key, D0, D1, D2, D3, D4); } \
  } } while (0)

#define T5_TAIL_STORE() \
  WMERGE_ALL(A0,A1,A2,A3,A4); \
  WMERGE_ALL(B0,B1,B2,B3,B4); \
  WMERGE_ALL(C0,C1,C2,C3,C4); \
  WMERGE_ALL(D0,D1,D2,D3,D4); \
  __shared__ u64 wbuf[4][20]; \
  int tid = threadIdx.x; \
  int wid = tid >> 6; \
  if ((tid & 63) == 0) { \
    u64* w = wbuf[wid]; \
    w[0]=A0; w[1]=A1; w[2]=A2; w[3]=A3; w[4]=A4; \
    w[5]=B0; w[6]=B1; w[7]=B2; w[8]=B3; w[9]=B4; \
    w[10]=C0; w[11]=C1; w[12]=C2; w[13]=C3; w[14]=C4; \
    w[15]=D0; w[16]=D1; w[17]=D2; w[18]=D3; w[19]=D4; \
  } \
  __syncthreads(); \
  if (tid == 0) { \
    _Pragma("unroll") \
    for (int w = 1; w < 4; ++w) { \
      _Pragma("unroll") \
      for (int j = 0; j < 5; ++j) { \
        u64 ka = wbuf[w][j];      INS5(ka, A0, A1, A2, A3, A4); \
        u64 kb = wbuf[w][5 + j];  INS5(kb, B0, B1, B2, B3, B4); \
        u64 kc = wbuf[w][10 + j]; INS5(kc, C0, C1, C2, C3, C4); \
        u64 kd = wbuf[w][15 + j]; INS5(kd, D0, D1, D2, D3, D4); \
      } \
    } \
    size_t nb = gridDim.x; \
    u64* o0 = outA + ((size_t)0 * nb + blockIdx.x) * 5; \
    o0[0]=A0; o0[1]=A1; o0[2]=A2; o0[3]=A3; o0[4]=A4; \
    u64* o1 = outA + ((size_t)1 * nb + blockIdx.x) * 5; \
    o1[0]=B0; o1[1]=B1; o1[2]=B2; o1[3]=B3; o1[4]=B4; \
    u64* o2 = outA + ((size_t)2 * nb + blockIdx.x) * 5; \
    o2[0]=C0; o2[1]=C1; o2[2]=C2; o2[3]=C3; o2[4]=C4; \
    u64* o3 = outA + ((size_t)3 * nb + blockIdx.x) * 5; \
    o3[0]=D0; o3[1]=D1; o3[2]=D2; o3[3]=D3; o3[4]=D4; \
  }

#define T5_HEAD() \
  int lb0 = labeled[0], lb1 = labeled[1], lb2 = labeled[2], lb3 = labeled[3]; \
  u32 half = (u32)(N / 2); \
  u32 ka0 = RK.ki[0][0], kb0 = RK.ki[0][1]; \
  u32 ka1 = RK.ki[1][0], kb1 = RK.ki[1][1]; \
  u32 ka2 = RK.ki[2][0], kb2 = RK.ki[2][1]; \
  u32 ka3 = RK.ki[3][0], kb3 = RK.ki[3][1]; \
  u64 A0=0,A1=0,A2=0,A3=0,A4=0; \
  u64 B0=0,B1=0,B2=0,B3=0,B4=0; \
  u64 C0=0,C1=0,C2=0,C3=0,C4=0; \
  u64 D0=0,D1=0,D2=0,D3=0,D4=0;

__global__ void k_top5A(const int* __restrict__ gt, const int* __restrict__ labeled,
                        RKeys RK, u64* __restrict__ outA, u8* __restrict__ ci8, int N) {
  T5_HEAD()
  int Nq = N >> 2;
  int stride = gridDim.x * blockDim.x;
  for (int q = blockIdx.x * blockDim.x + threadIdx.x; q < Nq; q += stride) {
    int4 g4 = ((const int4*)gt)[q];
    int n = q << 2;
    u8 c0v, c1v, c2v, c3v;
    T5PROC_THR(g4.x, n, c0v);
    T5PROC_THR(g4.y, n + 1, c1v);
    T5PROC_THR(g4.z, n + 2, c2v);
    T5PROC_THR(g4.w, n + 3, c3v);
    ((uchar4*)ci8)[q] = make_uchar4(c0v, c1v, c2v, c3v);
  }
  T5_TAIL_STORE()
}

__global__ void k_top5B(const u64* __restrict__ outA, u32* __restrict__ rescue,
                        u64* __restrict__ top5F, int nblk) {
  int i = blockIdx.x;  // class
  const u64* src = outA + (size_t)i * nblk * 5;
  u64 t0 = 0, t1 = 0, t2 = 0, t3 = 0, t4 = 0;
  int tot = nblk * 5;
  for (int j = threadIdx.x; j < tot; j += blockDim.x) { u64 k = src[j]; INS5(k, t0, t1, t2, t3, t4); }
  WMERGE_ALL(t0, t1, t2, t3, t4);
  __shared__ u64 wbuf[4 * 5];
  int tid = threadIdx.x;
  int wid = tid >> 6;
  if ((tid & 63) == 0) {
    wbuf[wid * 5 + 0] = t0; wbuf[wid * 5 + 1] = t1; wbuf[wid * 5 + 2] = t2;
    wbuf[wid * 5 + 3] = t3; wbuf[wid * 5 + 4] = t4;
  }
  __syncthreads();
  if (tid == 0) {
#pragma unroll
    for (int w = 1; w < 4; ++w)
#pragma unroll
      for (int j = 0; j < 5; ++j) { u64 k = wbuf[w * 5 + j]; INS5(k, t0, t1, t2, t3, t4); }
    u64* o = top5F + (size_t)i * 5;
    o[0] = t0; o[1] = t1; o[2] = t2; o[3] = t3; o[4] = t4;
    if (t4 == 0ULL) atomicOr(rescue, 1u << i);
  }
}

__global__ void k_top5A_resc(const int* __restrict__ gt, const int* __restrict__ labeled,
                             RKeys RK, const u32* __restrict__ rescue,
                             u64* __restrict__ outA, int N) {
  if ((rescue[0] & 0xFu) == 0u) return;
  T5_HEAD()
  int Nq = N >> 2;
  int stride = gridDim.x * blockDim.x;
  for (int q = blockIdx.x * blockDim.x + threadIdx.x; q < Nq; q += stride) {
    int4 g4 = ((const int4*)gt)[q];
    int n = q << 2;
    T5PROC(g4.x, n);
    T5PROC(g4.y, n + 1);
    T5PROC(g4.z, n + 2);
    T5PROC(g4.w, n + 3);
  }
  T5_TAIL_STORE()
}

__global__ void k_top5B_resc(const u64* __restrict__ outA, const u32* __restrict__ rescue,
                             u64* __restrict__ top5F, int nblk) {
  int i = blockIdx.x;
  if (!((rescue[0] >> i) & 1u)) return;
  const u64* src = outA + (size_t)i * nblk * 5;
  u64 t0 = 0, t1 = 0, t2 = 0, t3 = 0, t4 = 0;
  int tot = nblk * 5;
  for (int j = threadIdx.x; j < tot; j += blockDim.x) { u64 k = src[j]; INS5(k, t0, t1, t2, t3, t4); }
  WMERGE_ALL(t0, t1, t2, t3, t4);
  __shared__ u64 wbuf[4 * 5];
  int tid = threadIdx.x;
  int wid = tid >> 6;
  if ((tid & 63) == 0) {
    wbuf[wid * 5 + 0] = t0; wbuf[wid * 5 + 1] = t1; wbuf[wid * 5 + 2] = t2;
    wbuf[wid * 5 + 3] = t3; wbuf[wid * 5 + 4] = t4;
  }
  __syncthreads();
  if (tid == 0) {
#pragma unroll
    for (int w = 1; w < 4; ++w)
#pragma unroll
      for (int j = 0; j < 5; ++j) { u64 k = wbuf[w * 5 + j]; INS5(k, t0, t1, t2, t3, t4); }
    u64* o = top5F + (size_t)i * 5;
    o[0] = t0; o[1] = t1; o[2] = t2; o[3] = t3; o[4] = t4;
  }
}

// ---- transposed kmeans path (featsN stored fp16) ----

// float4 global reads, LDS transpose, fp16 (uint2 = 4 halves) writes.
__global__ void __launch_bounds__(256)
k_normT(const float4* __restrict__ feats4, uint2* __restrict__ featsH2, int N, int Z3) {
  __shared__ float xl[128 * 33];
  __shared__ float sinv[128];
  int tid = threadIdx.x;
  int nchunk = N >> 7;
  int Z3q = Z3 >> 2;
  for (int chunk = blockIdx.x; chunk < nchunk; chunk += gridDim.x) {
    int n0 = chunk << 7;
    int b = n0 / Z3, v0 = n0 - b * Z3;  // Z3 % 128 == 0: chunk within one b
    const float4* fb4 = feats4 + (size_t)b * DD * Z3q + (v0 >> 2);
#pragma unroll
    for (int j = 0; j < 4; ++j) {
      int idx = j * 256 + tid;          // 0..1023 float4 slots
      int d = idx >> 5, v4 = idx & 31;  // 32 float4 per d-row (128 floats)
      float4 f = fb4[(size_t)d * Z3q + v4];
      int vb = v4 << 2;
      xl[(vb + 0) * 33 + d] = f.x;
      xl[(vb + 1) * 33 + d] = f.y;
      xl[(vb + 2) * 33 + d] = f.z;
      xl[(vb + 3) * 33 + d] = f.w;
    }
    __syncthreads();
    if (tid < 128) {
      float s = 0.f;
#pragma unroll
      for (int d = 0; d < DD; ++d) { float x = xl[tid * 33 + d]; s += x * x; }
      sinv[tid] = 1.0f / sqrtf(s + 1e-12f);
    }
    __syncthreads();
#pragma unroll
    for (int j = 0; j < 4; ++j) {
      int idx = j * 256 + tid;
      int vox = idx >> 3, q = idx & 7;
      float iv = sinv[vox];
      float4 o;
      o.x = xl[vox * 33 + q * 4 + 0] * iv;
      o.y = xl[vox * 33 + q * 4 + 1] * iv;
      o.z = xl[vox * 33 + q * 4 + 2] * iv;
      o.w = xl[vox * 33 + q * 4 + 3] * iv;
      featsH2[(size_t)n0 * 8 + idx] = f4toh8(o);
    }
    __syncthreads();
  }
}

__global__ void k_initcentT(const u32* __restrict__ featsH,
                            const u64* __restrict__ top5F, float* __restrict__ cent, int N) {
  int t = threadIdx.x;
  if (t >= LBN * KMX * DD) return;
  int d = t & 31;
  int k = (t >> 5) % KMX;
  int i = t / (KMX * DD);
  u32 n = ~(u32)(top5F[(size_t)i * 5 + k]);
  if (n >= (u32)N) n = 0;
  const __half* fh = (const __half*)featsH;
  cent[(i * KMX + k) * DD + d] = __half2float(fh[(size_t)n * DD + d]);
}

// atomic-free, software-prefetched assignment (2 copies/wave, 4 masked steps),
// fp16 feature reads, ci8 class reads, part transposed [p][block].
__global__ void __launch_bounds__(256)
k_assignW2(const uint2* __restrict__ featsH2, const u8* __restrict__ ci8,
           const float* __restrict__ cent, float* __restrict__ part, int N, int NB) {
  __shared__ float sc[LBN * KMX * SCPAD];
  __shared__ float ssw[8][LBN * KMX * SCPAD];
  __shared__ float scn[LBN * KMX];
  __shared__ float scw[8][LBN * KMX];
  int tid = threadIdx.x;
  for (int t = tid; t < LBN * KMX * DD; t += 256) {
    int cl2 = t >> 5, d = t & 31;
    sc[cl2 * SCPAD + d] = cent[t];
  }
  for (int t = tid; t < 8 * LBN * KMX * SCPAD; t += 256) (&ssw[0][0])[t] = 0.f;
  for (int t = tid; t < 8 * LBN * KMX; t += 256) (&scw[0][0])[t] = 0.f;
  __syncthreads();
  if (tid < LBN * KMX) {
    float s = 0.f;
#pragma unroll
    for (int d = 0; d < DD; ++d) { float c = sc[tid * SCPAD + d]; s += c * c; }
    scn[tid] = s;
  }
  __syncthreads();
  int q = tid & 7;
  int grp = (tid >> 3) & 7;
  int wv = tid >> 6;
  int cpi = 2 * wv + (grp >> 2);
  float* myss = &ssw[cpi][0];
  float* mysc = &scw[cpi][0];
  int sstep = grp & 3;
  const float* scq = sc + q * 4;
  int nchunk = N >> 5;
  int chunk = blockIdx.x;
  if (chunk < nchunk) {
    uint2 h2 = featsH2[(size_t)chunk * 256 + tid];
    int cv = ci8[(chunk << 5) + (tid >> 3)];
    while (true) {
      int nxt = chunk + gridDim.x;
      bool has = nxt < nchunk;
      uint2 nh2 = make_uint2(0u, 0u); int ncv = 255;
      if (has) {
        nh2 = featsH2[(size_t)nxt * 256 + tid];
        ncv = ci8[(nxt << 5) + (tid >> 3)];
      }
      float4 f4 = h8tof4(h2);
      int ci = (cv == 255) ? -1 : cv;
      int basec = (ci < 0 ? 0 : ci) * KMX;
      float4 c0 = *(const float4*)(scq + (basec + 0) * SCPAD);
      float4 c1 = *(const float4*)(scq + (basec + 1) * SCPAD);
      float4 c2 = *(const float4*)(scq + (basec + 2) * SCPAD);
      float4 c3 = *(const float4*)(scq + (basec + 3) * SCPAD);
      float4 c4 = *(const float4*)(scq + (basec + 4) * SCPAD);
      float p0 = f4.x * c0.x + f4.y * c0.y + f4.z * c0.z + f4.w * c0.w;
      float p1 = f4.x * c1.x + f4.y * c1.y + f4.z * c1.z + f4.w * c1.w;
      float p2 = f4.x * c2.x + f4.y * c2.y + f4.z * c2.z + f4.w * c2.w;
      float p3 = f4.x * c3.x + f4.y * c3.y + f4.z * c3.z + f4.w * c3.w;
      float p4 = f4.x * c4.x + f4.y * c4.y + f4.z * c4.z + f4.w * c4.w;
#pragma unroll
      for (int o = 1; o < 8; o <<= 1) {
        p0 += __shfl_xor(p0, o, 64);
        p1 += __shfl_xor(p1, o, 64);
        p2 += __shfl_xor(p2, o, 64);
        p3 += __shfl_xor(p3, o, 64);
        p4 += __shfl_xor(p4, o, 64);
      }
      float bd = scn[basec + 0] - 2.0f * p0; int bk = 0;
      float d2;
      d2 = scn[basec + 1] - 2.0f * p1; if (d2 < bd) { bd = d2; bk = 1; }
      d2 = scn[basec + 2] - 2.0f * p2; if (d2 < bd) { bd = d2; bk = 2; }
      d2 = scn[basec + 3] - 2.0f * p3; if (d2 < bd) { bd = d2; bk = 3; }
      d2 = scn[basec + 4] - 2.0f * p4; if (d2 < bd) { bd = d2; bk = 4; }
      int cl = basec + bk;
#pragma unroll
      for (int s = 0; s < 4; ++s) {
        if (sstep == s && ci >= 0) {
          float* dst = myss + cl * SCPAD + q * 4;
          float4 cur = *(float4*)dst;
          cur.x += f4.x; cur.y += f4.y; cur.z += f4.z; cur.w += f4.w;
          *(float4*)dst = cur;
          if (q == 0) mysc[cl] += 1.0f;
        }
      }
      if (!has) break;
      chunk = nxt; h2 = nh2; cv = ncv;
    }
  }
  __syncthreads();
  // part transposed: part[p][block] -> coalesced reads in redupd
  for (int p = tid; p < 660; p += 256) {
    float v;
    if (p < 640) {
      int idx = (p >> 5) * SCPAD + (p & 31);
      v = ssw[0][idx] + ssw[1][idx] + ssw[2][idx] + ssw[3][idx]
        + ssw[4][idx] + ssw[5][idx] + ssw[6][idx] + ssw[7][idx];
    } else {
      int ik = p - 640;
      v = scw[0][ik] + scw[1][ik] + scw[2][ik] + scw[3][ik]
        + scw[4][ik] + scw[5][ik] + scw[6][ik] + scw[7][ik];
    }
    part[(size_t)p * NB + blockIdx.x] = v;
  }
}

// reduce + centroid update; empty clusters flag emptyMask (fixed by k_fixempty)
__global__ void k_redupdT(const float* __restrict__ part, float* __restrict__ cent,
                          float* __restrict__ sums, float* __restrict__ kcnt,
                          u32* __restrict__ emptyMask, int NB) {
  __shared__ float w4[8];
  int p = blockIdx.x;
  int tid = threadIdx.x;  // 256
  if (p < 640) {
    int ik = p >> 5;
    float s = 0.f, c = 0.f;
    for (int b2 = tid; b2 < NB; b2 += 256) {
      s += part[(size_t)p * NB + b2];
      c += part[(size_t)(640 + ik) * NB + b2];
    }
    s = rsum64(s); c = rsum64(c);
    int wid = tid >> 6;
    if ((tid & 63) == 0) { w4[wid] = s; w4[4 + wid] = c; }
    __syncthreads();
    if (tid == 0) {
      float S = w4[0] + w4[1] + w4[2] + w4[3];
      float C = w4[4] + w4[5] + w4[6] + w4[7];
      sums[p] = S;
      if (C > 0.f) cent[p] = S / fmaxf(C, 1.0f);
      else atomicOr(emptyMask, 1u << ik);
    }
  } else if (p < 660) {
    int ik = p - 640;
    float c = 0.f;
    for (int b2 = tid; b2 < NB; b2 += 256) c += part[(size_t)(640 + ik) * NB + b2];
    c = rsum64(c);
    int wid = tid >> 6;
    if ((tid & 63) == 0) w4[wid] = c;
    __syncthreads();
    if (tid == 0) kcnt[ik] = w4[0] + w4[1] + w4[2] + w4[3];
  }
}

// gated: exact fallback top-5 for empty clusters (runs only if emptyMask != 0)
__global__ void __launch_bounds__(1024)
k_fixempty(const u32* __restrict__ featsH, const int* __restrict__ gt,
           const int* __restrict__ labeled, RKeys RK, u32* __restrict__ emptyMask,
           float* __restrict__ cent, int iter, int N) {
  u32 mask = emptyMask[0];
  if (mask == 0u) return;
  __shared__ u64 wbuf[16 * 5];
  __shared__ u32 idxs[KMX];
  int tid = threadIdx.x;
  u32 halfF = (u32)(((u64)5 * (u64)N) / 2);
  for (int ci = 0; ci < LBN; ++ci) {
    if (((mask >> (ci * KMX)) & 0x1Fu) == 0u) continue;
    int c = labeled[ci];
    u32 fa = RK.kf[ci][0], fb = RK.kf[ci][1];
    u32 base = (u32)iter * (u32)N;
    u64 t0 = 0, t1 = 0, t2 = 0, t3 = 0, t4 = 0;
    for (int n = tid; n < N; n += 1024) {
      if (gt[n] != c) continue;
      u32 uk = jax_ukey(fa, fb, halfF, base + (u32)n);
      u64 key = ((u64)uk << 32) | (u32)(~(u32)n);
      INS5(key, t0, t1, t2, t3, t4);
    }
    WMERGE_ALL(t0, t1, t2, t3, t4);
    int wid = tid >> 6;
    if ((tid & 63) == 0) {
      wbuf[wid * 5 + 0] = t0; wbuf[wid * 5 + 1] = t1; wbuf[wid * 5 + 2] = t2;
      wbuf[wid * 5 + 3] = t3; wbuf[wid * 5 + 4] = t4;
    }
    __syncthreads();
    if (tid == 0) {
      for (int w = 1; w < 16; ++w)
        for (int j = 0; j < 5; ++j) { u64 k = wbuf[w * 5 + j]; INS5(k, t0, t1, t2, t3, t4); }
      idxs[0] = ~(u32)t0; idxs[1] = ~(u32)t1; idxs[2] = ~(u32)t2;
      idxs[3] = ~(u32)t3; idxs[4] = ~(u32)t4;
    }
    __syncthreads();
    if (tid < KMX * DD) {
      int k = tid >> 5, d = tid & 31;
      if ((mask >> (ci * KMX + k)) & 1u) {
        u32 n = idxs[k];
        if (n >= (u32)N) n = 0;
        const __half* fh = (const __half*)featsH;
        cent[(ci * KMX + k) * DD + d] = __half2float(fh[(size_t)n * DD + d]);
      }
    }
    __syncthreads();
  }
  if (tid == 0) emptyMask[0] = 0u;
}

__global__ void k_prepT(const uint2* __restrict__ featsH2,
                        const int* __restrict__ pseudo, const SelState* __restrict__ st,
                        const int* __restrict__ aidx, float4* __restrict__ afe4,
                        int* __restrict__ alab, int N) {
  int tid = threadIdx.x;
  int r = blockIdx.x * 32 + (tid >> 3);
  int q = tid & 7;
  if (r >= (int)st->target) return;
  int n = aidx[r];
  if ((u32)n >= (u32)N) n = 0;
  if (q == 0) {
    int lb = pseudo[n];
    alab[r] = lb < 0 ? 0 : (lb > NCLS - 1 ? NCLS - 1 : lb);
  }
  afe4[(size_t)r * 8 + q] = h8tof4(featsH2[(size_t)n * 8 + q]);
}

// ---- anchor selection: one-pass prefilter + parallel rank-count; gated radix rescue ----

__global__ void __launch_bounds__(256)
k_anchsel(const int* __restrict__ pseudo, RKeys RK, u64* __restrict__ cand4k,
          SelState* st, int N) {
  __shared__ u32 mcnt[4];
  u32 K0 = RK.k1000[0], K1 = RK.k1000[1];
  u32 half = (u32)(N / 2);
  int tid = threadIdx.x;
  int lcnt = 0;
  int stride = gridDim.x * blockDim.x;
  for (int n = blockIdx.x * blockDim.x + tid; n < N; n += stride) {
    bool valid = pseudo[n] > 0;
    lcnt += valid ? 1 : 0;
    u32 uk = jax_ukey(K0, K1, half, (u32)n);
    bool c = valid && (uk >= UKTHR);
    if (__ballot(c)) {
      if (c) {
        u32 p = atomicAdd(&st->ncand, 1u);
        if (p < (u32)ACAP) cand4k[p] = ((u64)uk << 32) | (u32)(~(u32)n);
      }
    }
  }
#pragma unroll
  for (int o = 32; o; o >>= 1) lcnt += __shfl_xor(lcnt, o, 64);
  if ((tid & 63) == 0) mcnt[tid >> 6] = (u32)lcnt;
  __syncthreads();
  if (tid == 0) atomicAdd(&st->M, mcnt[0] + mcnt[1] + mcnt[2] + mcnt[3]);
}

__global__ void k_selmode(SelState* st, u32* rescue) {
  if (threadIdx.x != 0 || blockIdx.x != 0) return;
  u32 M = st->M;
  u32 tgt = M < (u32)MAXA ? M : (u32)MAXA;
  st->target = tgt;
  if (!(st->ncand >= tgt && st->ncand <= (u32)ACAP)) rescue[1] = 1u;
}

__global__ void __launch_bounds__(256)
k_rank(const u64* __restrict__ cand4k, const SelState* __restrict__ st,
       const u32* __restrict__ rescue, int* __restrict__ aidx) {
  if (rescue[1]) return;
  __shared__ u64 keys[ACAP];
  u32 nc = st->ncand; if (nc > (u32)ACAP) nc = (u32)ACAP;
  u32 target = st->target;
  int tid = threadIdx.x;
  for (int t = tid; t < ACAP; t += 256) keys[t] = (t < (int)nc) ? cand4k[t] : 0ULL;
  __syncthreads();
  int i = blockIdx.x * 256 + tid;
  if (i >= (int)nc) return;
  u64 my = keys[i];
  u32 rank = 0;
  for (u32 j = 0; j < nc; ++j) rank += (keys[j] > my) ? 1u : 0u;
  if (rank < target) aidx[rank] = (int)(~(u32)my);
}

// -- gated radix rescue chain --

__global__ void k_svinit(const int* __restrict__ pseudo, RKeys RK, const u32* __restrict__ rescue,
                         u32* __restrict__ sv, u32* __restrict__ hist, int N) {
  if (!rescue[1]) return;
  __shared__ u32 h[2048];
  for (int t = threadIdx.x; t < 2048; t += blockDim.x) h[t] = 0;
  __syncthreads();
  u32 half = (u32)(N / 2);
  u32 K0 = RK.k1000[0], K1 = RK.k1000[1];
  int Nq = N >> 2;
  int stride = gridDim.x * blockDim.x;
  for (int q = blockIdx.x * blockDim.x + threadIdx.x; q < Nq; q += stride) {
    int4 p4 = ((const int4*)pseudo)[q];
    int n = q << 2;
    u32 s0 = 0, s1 = 0, s2 = 0, s3 = 0;
    if (p4.x > 0) { s0 = jax_ukey(K0, K1, half, (u32)n);     atomicAdd(&h[s0 >> 21], 1u); }
    if (p4.y > 0) { s1 = jax_ukey(K0, K1, half, (u32)n + 1); atomicAdd(&h[s1 >> 21], 1u); }
    if (p4.z > 0) { s2 = jax_ukey(K0, K1, half, (u32)n + 2); atomicAdd(&h[s2 >> 21], 1u); }
    if (p4.w > 0) { s3 = jax_ukey(K0, K1, half, (u32)n + 3); atomicAdd(&h[s3 >> 21], 1u); }
    ((uint4*)sv)[q] = make_uint4(s0, s1, s2, s3);
  }
  __syncthreads();
  for (int t = threadIdx.x; t < 2048; t += blockDim.x) if (h[t]) atomicAdd(&hist[t], h[t]);
}

__global__ void k_hist12(const u32* __restrict__ sv, u32* __restrict__ hist,
                         const SelState* __restrict__ st, const u32* __restrict__ rescue,
                         int pass, int N) {
  if (!rescue[1]) return;
  __shared__ u32 h[2048];
  for (int t = threadIdx.x; t < 2048; t += blockDim.x) h[t] = 0;
  __syncthreads();
  u32 pre = (pass == 1) ? st->prefix1 : st->prefix21;
  int Nq = N >> 2;
  int stride = gridDim.x * blockDim.x;
  for (int q = blockIdx.x * blockDim.x + threadIdx.x; q < Nq; q += stride) {
    uint4 s4 = ((const uint4*)sv)[q];
#define H12(s_) do { u32 s = (s_); if (s) { \
      if (pass == 1) { if ((s >> 21) == pre) atomicAdd(&h[(s >> 10) & 0x7FFu], 1u); } \
      else           { if ((s >> 10) == pre) atomicAdd(&h[s & 0x3FFu], 1u); } } } while (0)
    H12(s4.x); H12(s4.y); H12(s4.z); H12(s4.w);
#undef H12
  }
  __syncthreads();
  for (int t = threadIdx.x; t < 2048; t += blockDim.x) if (h[t]) atomicAdd(&hist[t], h[t]);
}

__global__ void k_scan(const u32* __restrict__ hist, SelState* st,
                       const u32* __restrict__ rescue, int pass) {
  if (!rescue[1]) return;
  __shared__ u32 h[2048];
  __shared__ u32 csum[256];
  __shared__ u32 sh_rank;
  __shared__ int sh_found;
  __shared__ u32 sh_rem;
  int tid = threadIdx.x;  // 256
  int nb = (pass == 2) ? 1024 : 2048;
  for (int t = tid; t < 2048; t += 256) h[t] = (t < nb) ? hist[t] : 0u;
  __syncthreads();
  u32 cs = 0;
#pragma unroll
  for (int j = 0; j < 8; ++j) cs += h[tid * 8 + j];
  csum[tid] = cs;
  __syncthreads();
  if (tid == 0) {
    sh_rank = (pass == 0) ? st->target : (pass == 1 ? st->rank1 : st->rank2);
    sh_found = -1;
    sh_rem = 0;
  }
  __syncthreads();
  u32 rank = sh_rank;
  if (rank > 0) {
    u32 above = 0;
    for (int j = tid + 1; j < 256; ++j) above += csum[j];
    u32 run = above;
    for (int b = tid * 8 + 7; b >= tid * 8; --b) {
      u32 c = h[b];
      if (run < rank && rank <= run + c) { sh_found = b; sh_rem = rank - run; }
      run += c;
    }
  }
  __syncthreads();
  if (tid == 0) {
    int found = sh_found;
    u32 rem = sh_rem;
    if (pass == 0) {
      if (found < 0) { st->prefix1 = 0xFFFFFFFFu; st->rank1 = 0; }
      else { st->prefix1 = (u32)found; st->rank1 = rem; }
    } else if (pass == 1) {
      if (found < 0) { st->prefix21 = 0xFFFFFFFFu; st->rank2 = 0; }
      else { st->prefix21 = (st->prefix1 << 11) | (u32)found; st->rank2 = rem; }
    } else {
      if (found < 0) st->pivot_sv = 0xFFFFFFFFu;
      else st->pivot_sv = (st->prefix21 << 10) | (u32)found;
    }
  }
}

__global__ void k_gather(const u32* __restrict__ sv, SelState* st,
                         const u32* __restrict__ rescue, u64* __restrict__ cand, int N) {
  if (!rescue[1]) return;
  if (st->target == 0) return;
  u32 piv = st->pivot_sv;
  int Nq = N >> 2;
  int stride = gridDim.x * blockDim.x;
  for (int q = blockIdx.x * blockDim.x + threadIdx.x; q < Nq; q += stride) {
    uint4 s4 = ((const uint4*)sv)[q];
    int n = q << 2;
#define GPUSH(s_, nn_) do { u32 s = (s_); \
    if (s && s >= piv) { u32 p = atomicAdd(&st->ncand2, 1u); \
      if (p < 4096u) cand[p] = ((u64)s << 32) | (u32)(~(u32)(nn_)); } } while (0)
    GPUSH(s4.x, n); GPUSH(s4.y, n + 1); GPUSH(s4.z, n + 2); GPUSH(s4.w, n + 3);
#undef GPUSH
  }
}

__global__ void __launch_bounds__(1024) k_sortsel(const u64* __restrict__ cand,
                                                  const SelState* __restrict__ st,
                                                  const u32* __restrict__ rescue,
                                                  int* __restrict__ aidx) {
  if (!rescue[1]) return;
  __shared__ u64 s[4096];
  u32 nc = st->ncand2; if (nc > 4096u) nc = 4096u;
  u32 target = st->target;
  for (int t = threadIdx.x; t < 4096; t += blockDim.x) s[t] = (t < (int)nc) ? cand[t] : 0ULL;
  __syncthreads();
  for (u32 ksz = 2; ksz <= 4096; ksz <<= 1) {
    for (u32 j = ksz >> 1; j > 0; j >>= 1) {
      for (u32 idx = threadIdx.x; idx < 4096; idx += blockDim.x) {
        u32 ixj = idx ^ j;
        if (ixj > idx) {
          bool up = (idx & ksz) == 0;
          u64 A = s[idx], B = s[ixj];
          bool sw = up ? (A < B) : (A > B);
          if (sw) { s[idx] = B; s[ixj] = A; }
        }
      }
      __syncthreads();
    }
  }
  for (int t = threadIdx.x; t < MAXA; t += blockDim.x)
    if (t < (int)target) aidx[t] = (int)(~(u32)s[t]);
}

// ---- shared tail ----

__global__ void k_anchor_final(const float* __restrict__ cent, const float* __restrict__ sums,
                               const float* __restrict__ kcnt, const float* __restrict__ protn,
                               const int* __restrict__ labeled, float* __restrict__ accum) {
  int i = blockIdx.x;
  int d = threadIdx.x;
  if (d >= DD) return;
  int c = labeled[i];
  float cnt = 0.f;
#pragma unroll
  for (int k = 0; k < KMX; ++k) cnt += kcnt[i * KMX + k];
  int cs = c < 0 ? 0 : (c > NCLS - 1 ? NCLS - 1 : c);
  float part = 0.f;
  if (cnt >= (float)KMX) {
#pragma unroll
    for (int k = 0; k < KMX; ++k) {
      float v = cent[(i * KMX + k) * DD + d];
      float s = rsum32(v * v);
      float dn1 = sqrtf(s + 1e-12f);
      float v1 = v / dn1;
      float s2 = rsum32(v1 * v1);
      float dn2 = sqrtf(s2 + 1e-12f);
      float vv = v1 / dn2;
      float df = protn[(cs * KMX + k) * DD + d] - vv;
      part += df * df;
    }
  } else {
    float mv = 0.f;
#pragma unroll
    for (int k = 0; k < KMX; ++k) mv += sums[(i * KMX + k) * DD + d];
    mv /= fmaxf(cnt, 1.0f);
    float s = rsum32(mv * mv);
    float dn = sqrtf(s + 1e-12f);
    float vv = mv / dn;
#pragma unroll
    for (int k = 0; k < KMX; ++k) {
      float df = protn[(cs * KMX + k) * DD + d] - vv;
      part += df * df;
    }
  }
  float ls = rsum32(part) * (1.0f / (KMX * DD));
  bool valid = (c != 0) && (c < NCLS) && (cnt > 0.f);
  if (d == 0 && valid) { atomicAdd(&accum[0], ls); atomicAdd(&accum[1], 1.0f); }
}

__global__ void k_triplet(const float* __restrict__ protn, const float* __restrict__ afe,
                          const int* __restrict__ alab, const SelState* __restrict__ st,
                          RKeys RK, float* __restrict__ acc) {
  __shared__ float pn[CKK * DD];
  __shared__ float spn[CKK];
  int tid = threadIdx.x;
  for (int t = tid; t < CKK * DD; t += blockDim.x) pn[t] = protn[t];
  __syncthreads();
  if (tid < CKK) {
    float s = 0.f;
    for (int d = 0; d < DD; ++d) s += pn[tid * DD + d] * pn[tid * DD + d];
    spn[tid] = s;
  }
  __syncthreads();
  int r = blockIdx.x * blockDim.x + tid;
  if (r >= (int)st->target) return;
  float a[DD]; float sa = 0.f;
#pragma unroll
  for (int d = 0; d < DD; ++d) { a[d] = afe[(size_t)r * DD + d]; sa += a[d] * a[d]; }
  int lab = alab[r];
  int ob = lab * KMX;
  float bs = -3.4e38f; int pidx = ob;
  float pos_d = 3.4e38f;
  for (int k = ob; k < ob + KMX; ++k) {
    float dot = 0.f;
#pragma unroll
    for (int d = 0; d < DD; ++d) dot += a[d] * pn[k * DD + d];
    if (dot > bs) { bs = dot; pidx = k; }
    float d2 = (sa + spn[k]) - 2.0f * dot;
    float dd = sqrtf(fmaxf(d2, 0.f));
    pos_d = fminf(pos_d, dd);
  }
  u32 halfT = (u32)(MAXA * CKK / 2);
  bool any_semi = false;
  u32 bu1 = 0; int k1i = 0;
  u32 bu2 = 0; int k2i = 0;
  for (int k = 0; k < CKK; ++k) {
    if (k / KMX == lab) continue;
    float dot = 0.f;
#pragma unroll
    for (int d = 0; d < DD; ++d) dot += a[d] * pn[k * DD + d];
    float d2 = (sa + spn[k]) - 2.0f * dot;
    float dd = sqrtf(fmaxf(d2, 0.f));
    u32 j = (u32)(r * CKK + k);
    bool semi = (dd > pos_d) && (dd < pos_d + 1.0f);
    if (semi) {
      u32 u1 = jax_ukey(RK.k2000[0], RK.k2000[1], halfT, j);
      any_semi = true;
      if (u1 > bu1) { bu1 = u1; k1i = k; }
    }
    u32 u2 = jax_ukey(RK.k2001[0], RK.k2001[1], halfT, j);
    if (u2 > bu2) { bu2 = u2; k2i = k; }
  }
  int nidx = any_semi ? k1i : k2i;
  float aden = sqrtf(sa + 1e-12f);
  float pden = sqrtf(spn[pidx] + 1e-12f);
  float nden = sqrtf(spn[nidx] + 1e-12f);
  float s1 = 0.f, s2 = 0.f;
#pragma unroll
  for (int d = 0; d < DD; ++d) {
    float an = a[d] / aden;
    float pv = pn[pidx * DD + d] / pden;
    float nv = pn[nidx * DD + d] / nden;
    float t1 = an - pv; s1 += t1 * t1;
    float t2 = an - nv; s2 += t2 * t2;
  }
  float d_pos = sqrtf(s1 + 1e-12f);
  float d_neg = sqrtf(s2 + 1e-12f);
  float xx = (d_pos - d_neg) + 1.0f;
  float l = fmaxf(xx, 0.f) + log1pf(expf(-fabsf(xx)));
  atomicAdd(&acc[0], l);
  atomicAdd(&acc[1], 1.0f);
}

__global__ void k_final(const float* __restrict__ anchor_acc, const float* __restrict__ proto_acc,
                        const float* __restrict__ compact, float* __restrict__ out) {
  if (threadIdx.x != 0 || blockIdx.x != 0) return;
  float al = anchor_acc[0] / fmaxf(anchor_acc[1], 1.0f);
  float pl = proto_acc[0] / fmaxf(proto_acc[1], 1.0f);
  out[0] = pl + 1.0f * al + 0.1f * compact[0];
}

// ---------------- host ----------------

static void host_keys(RKeys* K) {
  const u32 b0 = 0u, b1 = 42u;
  u32 o0, o1;
  for (int i = 0; i < LBN; ++i) {
    u32 f0, f1;
    tf2x32(b0, b1, 0u, (u32)i, &f0, &f1);
    u32 p0, q0, p1, q1;
    tf2x32(f0, f1, 0u, 2u, &p0, &q0);
    tf2x32(f0, f1, 1u, 3u, &p1, &q1);
    K->ki[i][0] = p0; K->ki[i][1] = p1;
    K->kf[i][0] = q0; K->kf[i][1] = q1;
  }
  tf2x32(b0, b1, 0u, 1000u, &o0, &o1); K->k1000[0] = o0; K->k1000[1] = o1;
  tf2x32(b0, b1, 0u, 2000u, &o0, &o1); K->k2000[0] = o0; K->k2000[1] = o1;
  tf2x32(b0, b1, 0u, 2001u, &o0, &o1); K->k2001[0] = o0; K->k2001[1] = o1;
}

extern "C" void kernel_launch(void* const* d_in, const int* in_sizes, int n_in,
                              void* d_out, int out_size, void* d_ws, size_t ws_size,
                              hipStream_t stream) {
  const float* feats = (const float*)d_in[0];
  const float* protos = (const float*)d_in[1];
  const int* pseudo = (const int*)d_in[2];
  const int* gt = (const int*)d_in[3];
  const int* labeled = (const int*)d_in[4];
  float* out = (float*)d_out;

  int N = in_sizes[2];
  int Z3 = N / 4;

  RKeys RK;
  host_keys(&RK);

  const int nbas[3] = {1536, 768, 384};
  for (int attempt = 0; attempt < 3; ++attempt) {
    int NBAS = nbas[attempt];
    char* W = (char*)d_ws;
    size_t off = 0;
    auto alloc = [&](size_t bytes) -> char* {
      char* p = W + off;
      off += (bytes + 255) & ~(size_t)255;
      return p;
    };
    char* zeroBase = W + off;
    u32* hist3 = (u32*)alloc(3 * 2048 * 4);
    SelState* st = (SelState*)alloc(256);
    float* anchor_acc = (float*)alloc(256);
    float* proto_acc = (float*)alloc(256);
    u32* rescue = (u32*)alloc(256);  // [0]=top5 class mask, [1]=anchor rescue, [2]=emptyMask
    size_t zeroBytes = (size_t)((W + off) - zeroBase);
    u64* cand4k = (u64*)alloc((size_t)ACAP * 8);
    u64* outA = (u64*)alloc((size_t)LBN * NBLKA * 5 * 8);
    u64* top5F = (u64*)alloc((size_t)LBN * 5 * 8);
    float* cent = (float*)alloc((size_t)LBN * KMX * DD * 4);
    float* sums = (float*)alloc((size_t)LBN * KMX * DD * 4);
    float* kcnt = (float*)alloc((size_t)LBN * KMX * 4);
    float* protn = (float*)alloc((size_t)CKK * DD * 4);
    float* compact = (float*)alloc(256);
    u32* sv = (u32*)alloc((size_t)N * 4);
    float* part = (float*)alloc((size_t)680 * NBAS * 4);
    u64* cand = (u64*)alloc(4096 * 8);
    int* aidx = (int*)alloc((size_t)MAXA * 4);
    int* alab = (int*)alloc((size_t)MAXA * 4);
    float* afe = (float*)alloc((size_t)MAXA * DD * 4);
    u32* featsH = (u32*)alloc((size_t)N * DD * 2);  // fp16 normalized features
    u8* ci8 = (u8*)alloc((size_t)N);                // per-voxel class index
    if (ws_size < off) continue;

    hipMemsetAsync(zeroBase, 0, zeroBytes, stream);

    k_protos<<<dim3(1), dim3(256), 0, stream>>>(protos, protn, compact);

    // top-5 init selection (kind 0 only) + ci8 materialization; gated exact rescue
    k_top5A<<<dim3(NBLKA), dim3(256), 0, stream>>>(gt, labeled, RK, outA, ci8, N);
    k_top5B<<<dim3(LBN), dim3(256), 0, stream>>>(outA, rescue, top5F, NBLKA);
    k_top5A_resc<<<dim3(NBLKA), dim3(256), 0, stream>>>(gt, labeled, RK, rescue, outA, N);
    k_top5B_resc<<<dim3(LBN), dim3(256), 0, stream>>>(outA, rescue, top5F, NBLKA);

    uint2* featsH2 = (uint2*)featsH;
    k_normT<<<dim3(4096), dim3(256), 0, stream>>>((const float4*)feats, featsH2, N, Z3);
    k_initcentT<<<dim3(1), dim3(LBN * KMX * DD), 0, stream>>>(featsH, top5F, cent, N);
    for (int it = 0; it < KIT; ++it) {
      k_assignW2<<<dim3(NBAS), dim3(256), 0, stream>>>(featsH2, ci8, cent, part, N, NBAS);
      k_redupdT<<<dim3(660), dim3(256), 0, stream>>>(part, cent, sums, kcnt, rescue + 2, NBAS);
      k_fixempty<<<dim3(1), dim3(1024), 0, stream>>>(featsH, gt, labeled, RK, rescue + 2, cent, it, N);
    }
    k_anchor_final<<<dim3(LBN), dim3(64), 0, stream>>>(cent, sums, kcnt, protn, labeled, anchor_acc);

    // anchor selection: one-pass prefilter; rank-count; gated radix rescue
    k_anchsel<<<dim3(2048), dim3(256), 0, stream>>>(pseudo, RK, cand4k, st, N);
    k_selmode<<<dim3(1), dim3(64), 0, stream>>>(st, rescue);
    k_svinit<<<dim3(1024), dim3(256), 0, stream>>>(pseudo, RK, rescue, sv, hist3, N);
    k_scan<<<dim3(1), dim3(256), 0, stream>>>(hist3, st, rescue, 0);
    k_hist12<<<dim3(1024), dim3(256), 0, stream>>>(sv, hist3 + 2048, st, rescue, 1, N);
    k_scan<<<dim3(1), dim3(256), 0, stream>>>(hist3 + 2048, st, rescue, 1);
    k_hist12<<<dim3(1024), dim3(256), 0, stream>>>(sv, hist3 + 4096, st, rescue, 2, N);
    k_scan<<<dim3(1), dim3(256), 0, stream>>>(hist3 + 4096, st, rescue, 2);
    k_gather<<<dim3(1024), dim3(256), 0, stream>>>(sv, st, rescue, cand, N);
    k_sortsel<<<dim3(1), dim3(1024), 0, stream>>>(cand, st, rescue, aidx);
    k_rank<<<dim3(ACAP / 256), dim3(256), 0, stream>>>(cand4k, st, rescue, aidx);

    k_prepT<<<dim3(MAXA / 32), dim3(256), 0, stream>>>(featsH2, pseudo, st, aidx,
                                                        (float4*)afe, alab, N);
    k_triplet<<<dim3(MAXA / 256), dim3(256), 0, stream>>>(protn, afe, alab, st, RK, proto_acc);

    k_final<<<dim3(1), dim3(64), 0, stream>>>(anchor_acc, proto_acc, compact, out);
    return;
  }
}